// Round 1
// baseline (3308.239 us; speedup 1.0000x reference)
//
#include <hip/hip_runtime.h>
#include <hip/hip_bf16.h>

// MHSA fp32 baseline: B=2, S=2048, H=2048, NH=16, D=128.
// Round 0: correctness-first tiled fp32 (no MFMA yet). Establishes layouts:
//   ws: Q|K|V as [B][NH][S][D], AO as [M][H] (M = B*S = 4096).
// Next rounds: split-bf16 MFMA GEMMs (hi/lo, 3 mfma per k-step).

#define Bc 2
#define Sc 2048
#define Hc 2048
#define NHc 16
#define Dc 128
#define Mc 4096   // B*S

// ---------------------------------------------------------------------------
// Fused QKV projection: Y = X @ W + b for W in {Wq,Wk,Wv}; scatter to
// [B][NH][S][D]. 64x64 output tile, BK=16, 256 threads, 4x4 per thread.
// grid = (96, 64): x = 32 col-tiles per weight * 3 weights, y = row tiles.
// ---------------------------------------------------------------------------
__global__ __launch_bounds__(256) void qkv_gemm(
    const float* __restrict__ X,
    const float* __restrict__ Wq, const float* __restrict__ bq,
    const float* __restrict__ Wk, const float* __restrict__ bk,
    const float* __restrict__ Wv, const float* __restrict__ bv,
    float* __restrict__ Q, float* __restrict__ K, float* __restrict__ V)
{
    const int ct    = blockIdx.x;
    const int which = ct >> 5;            // 0=Q,1=K,2=V
    const int n0    = (ct & 31) * 64;     // col tile within H
    const int m0    = blockIdx.y * 64;    // row tile within M

    const float* W    = (which == 0) ? Wq : (which == 1) ? Wk : Wv;
    const float* bias = (which == 0) ? bq : (which == 1) ? bk : bv;
    float*       O    = (which == 0) ? Q  : (which == 1) ? K  : V;

    __shared__ float As[16][64];   // [k][m]
    __shared__ float Bs[16][64];   // [k][n]

    const int tid = threadIdx.x;
    const int tx  = tid & 15;      // 0..15 -> 4 cols each
    const int ty  = tid >> 4;      // 0..15 -> 4 rows each

    float acc[4][4] = {};

    for (int k0 = 0; k0 < Hc; k0 += 16) {
        // A tile: rows m0..+63, cols k0..+15 (transposed into LDS)
        {
            const int row = tid >> 2;   // 0..63
            const int kq  = tid & 3;    // float4 within 16
            const float4 v = *(const float4*)(X + (size_t)(m0 + row) * Hc + k0 + kq * 4);
            As[kq * 4 + 0][row] = v.x;
            As[kq * 4 + 1][row] = v.y;
            As[kq * 4 + 2][row] = v.z;
            As[kq * 4 + 3][row] = v.w;
        }
        // B tile: rows k0..+15, cols n0..+63 (straight)
        {
            const int row = tid >> 4;   // 0..15
            const int nq  = tid & 15;   // 0..15
            *(float4*)&Bs[row][nq * 4] =
                *(const float4*)(W + (size_t)(k0 + row) * Hc + n0 + nq * 4);
        }
        __syncthreads();
#pragma unroll
        for (int k = 0; k < 16; ++k) {
            const float4 a = *(const float4*)&As[k][ty * 4];
            const float4 b = *(const float4*)&Bs[k][tx * 4];
            const float av[4] = {a.x, a.y, a.z, a.w};
            const float bv4[4] = {b.x, b.y, b.z, b.w};
#pragma unroll
            for (int i = 0; i < 4; ++i)
#pragma unroll
                for (int j = 0; j < 4; ++j)
                    acc[i][j] += av[i] * bv4[j];
        }
        __syncthreads();
    }

    // Epilogue: bias + scatter to [B][NH][S][D]
    const int ncol = n0 + tx * 4;
    const int h    = ncol >> 7;       // /128
    const int d    = ncol & 127;
    const float4 bi = *(const float4*)(bias + ncol);
#pragma unroll
    for (int i = 0; i < 4; ++i) {
        const int m = m0 + ty * 4 + i;
        const int b = m >> 11;        // /2048
        const int s = m & 2047;
        float4 r;
        r.x = acc[i][0] + bi.x;
        r.y = acc[i][1] + bi.y;
        r.z = acc[i][2] + bi.z;
        r.w = acc[i][3] + bi.w;
        *(float4*)&O[(((size_t)b * NHc + h) * Sc + s) * Dc + d] = r;
    }
}

// ---------------------------------------------------------------------------
// Flash-style attention. One block per (q-tile of 64 rows, head, batch).
// Streams K/V 64 rows at a time, online softmax, O accumulated in registers.
// 256 threads: scores 4x4/thread (16x16 grid), O is 4 rows x 8 cols/thread.
// ---------------------------------------------------------------------------
__global__ __launch_bounds__(256) void attn_kernel(
    const float* __restrict__ Qg, const float* __restrict__ Kg,
    const float* __restrict__ Vg, float* __restrict__ AO)
{
    const int qt = blockIdx.x;   // 0..31
    const int h  = blockIdx.y;   // 0..15
    const int b  = blockIdx.z;   // 0..1

    const float* Qp = Qg + ((size_t)b * NHc + h) * Sc * Dc;
    const float* Kp = Kg + ((size_t)b * NHc + h) * Sc * Dc;
    const float* Vp = Vg + ((size_t)b * NHc + h) * Sc * Dc;

    __shared__ float Qs[128][64];    // [d][m]
    __shared__ float Ks[128][64];    // [d][n]
    __shared__ float Vs[64][132];    // [n][d] (+4 pad)
    __shared__ float Ps[64][68];     // scores/probs (+4 pad, 16B-aligned rows)
    __shared__ float pmax[64][4], psum[64][4];
    __shared__ float mrow[64], lrow[64], arow[64];

    const int tid = threadIdx.x;
    const int tx  = tid & 15;
    const int ty  = tid >> 4;

    // Stage Q tile transposed: [m][d] global -> Qs[d][m]
#pragma unroll
    for (int it = 0; it < 8; ++it) {
        const int m  = tid >> 2;              // 0..63
        const int dq = (tid & 3) + it * 4;    // 0..31 (float4 index)
        const float4 v = *(const float4*)(Qp + (size_t)(qt * 64 + m) * Dc + dq * 4);
        Qs[dq * 4 + 0][m] = v.x;
        Qs[dq * 4 + 1][m] = v.y;
        Qs[dq * 4 + 2][m] = v.z;
        Qs[dq * 4 + 3][m] = v.w;
    }
    if (tid < 64) { mrow[tid] = -1e30f; lrow[tid] = 0.0f; }

    float o[4][8] = {};
    __syncthreads();

    const float sc = 0.08838834764831845f;  // 1/sqrt(128)

    for (int nt = 0; nt < 32; ++nt) {
        // Stage K (transposed) and V (straight) tiles
#pragma unroll
        for (int it = 0; it < 8; ++it) {
            const int n  = tid >> 2;
            const int dq = (tid & 3) + it * 4;
            const float4 kv = *(const float4*)(Kp + (size_t)(nt * 64 + n) * Dc + dq * 4);
            Ks[dq * 4 + 0][n] = kv.x;
            Ks[dq * 4 + 1][n] = kv.y;
            Ks[dq * 4 + 2][n] = kv.z;
            Ks[dq * 4 + 3][n] = kv.w;
            const float4 vv = *(const float4*)(Vp + (size_t)(nt * 64 + n) * Dc + dq * 4);
            *(float4*)&Vs[n][dq * 4] = vv;
        }
        __syncthreads();

        // Scores: s[i][j] = sum_d Qs[d][ty*4+i] * Ks[d][tx*4+j]
        float s[4][4] = {};
        for (int kk = 0; kk < 128; ++kk) {
            const float4 a = *(const float4*)&Qs[kk][ty * 4];
            const float4 bb = *(const float4*)&Ks[kk][tx * 4];
            const float av[4] = {a.x, a.y, a.z, a.w};
            const float bv4[4] = {bb.x, bb.y, bb.z, bb.w};
#pragma unroll
            for (int i = 0; i < 4; ++i)
#pragma unroll
                for (int j = 0; j < 4; ++j)
                    s[i][j] += av[i] * bv4[j];
        }
#pragma unroll
        for (int i = 0; i < 4; ++i) {
            float4 r;
            r.x = s[i][0] * sc; r.y = s[i][1] * sc;
            r.z = s[i][2] * sc; r.w = s[i][3] * sc;
            *(float4*)&Ps[ty * 4 + i][tx * 4] = r;
        }
        __syncthreads();

        // Softmax phase A: partial row max (4 threads per row, 16 cols each)
        {
            const int r = tid >> 2, q = tid & 3;
            float mx = -1e30f;
#pragma unroll
            for (int c = 0; c < 16; ++c) mx = fmaxf(mx, Ps[r][q * 16 + c]);
            pmax[r][q] = mx;
        }
        __syncthreads();
        // Phase B: combine max, compute alpha
        if (tid < 64) {
            const float mold = mrow[tid];
            float mx = fmaxf(fmaxf(pmax[tid][0], pmax[tid][1]),
                             fmaxf(pmax[tid][2], pmax[tid][3]));
            mx = fmaxf(mold, mx);
            mrow[tid] = mx;
            arow[tid] = __expf(mold - mx);
        }
        __syncthreads();
        // Phase C: exponentiate + partial sums; rescale O accumulators
        {
            const int r = tid >> 2, q = tid & 3;
            const float mx = mrow[r];
            float sum = 0.0f;
#pragma unroll
            for (int c = 0; c < 16; ++c) {
                const float p = __expf(Ps[r][q * 16 + c] - mx);
                Ps[r][q * 16 + c] = p;
                sum += p;
            }
            psum[r][q] = sum;
        }
#pragma unroll
        for (int i = 0; i < 4; ++i) {
            const float al = arow[ty * 4 + i];
#pragma unroll
            for (int j = 0; j < 8; ++j) o[i][j] *= al;
        }
        __syncthreads();
        // Phase D: fold partial sums into l; PV accumulate
        if (tid < 64)
            lrow[tid] = lrow[tid] * arow[tid] +
                        psum[tid][0] + psum[tid][1] + psum[tid][2] + psum[tid][3];
        for (int n = 0; n < 64; ++n) {
            const float p0 = Ps[ty * 4 + 0][n];
            const float p1 = Ps[ty * 4 + 1][n];
            const float p2 = Ps[ty * 4 + 2][n];
            const float p3 = Ps[ty * 4 + 3][n];
            const float4 v0 = *(const float4*)&Vs[n][tx * 8];
            const float4 v1 = *(const float4*)&Vs[n][tx * 8 + 4];
            const float vv[8] = {v0.x, v0.y, v0.z, v0.w, v1.x, v1.y, v1.z, v1.w};
#pragma unroll
            for (int j = 0; j < 8; ++j) {
                o[0][j] += p0 * vv[j];
                o[1][j] += p1 * vv[j];
                o[2][j] += p2 * vv[j];
                o[3][j] += p3 * vv[j];
            }
        }
        __syncthreads();
    }

    // Finalize: divide by l, write AO[m][h*128 + d]  (m = b*S + s)
#pragma unroll
    for (int i = 0; i < 4; ++i) {
        const int srow = qt * 64 + ty * 4 + i;
        const float inv = 1.0f / lrow[ty * 4 + i];
        float* dst = AO + ((size_t)b * Sc + srow) * Hc + h * Dc + tx * 8;
        float4 r0, r1;
        r0.x = o[i][0] * inv; r0.y = o[i][1] * inv;
        r0.z = o[i][2] * inv; r0.w = o[i][3] * inv;
        r1.x = o[i][4] * inv; r1.y = o[i][5] * inv;
        r1.z = o[i][6] * inv; r1.w = o[i][7] * inv;
        *(float4*)dst = r0;
        *(float4*)(dst + 4) = r1;
    }
}

// ---------------------------------------------------------------------------
// Output projection: out = AO @ Wo + bo. Same tiling as qkv_gemm, straight
// row-major output. grid = (32, 64).
// ---------------------------------------------------------------------------
__global__ __launch_bounds__(256) void out_gemm(
    const float* __restrict__ A, const float* __restrict__ W,
    const float* __restrict__ bias, float* __restrict__ O)
{
    const int n0 = blockIdx.x * 64;
    const int m0 = blockIdx.y * 64;

    __shared__ float As[16][64];
    __shared__ float Bs[16][64];

    const int tid = threadIdx.x;
    const int tx  = tid & 15;
    const int ty  = tid >> 4;

    float acc[4][4] = {};

    for (int k0 = 0; k0 < Hc; k0 += 16) {
        {
            const int row = tid >> 2;
            const int kq  = tid & 3;
            const float4 v = *(const float4*)(A + (size_t)(m0 + row) * Hc + k0 + kq * 4);
            As[kq * 4 + 0][row] = v.x;
            As[kq * 4 + 1][row] = v.y;
            As[kq * 4 + 2][row] = v.z;
            As[kq * 4 + 3][row] = v.w;
        }
        {
            const int row = tid >> 4;
            const int nq  = tid & 15;
            *(float4*)&Bs[row][nq * 4] =
                *(const float4*)(W + (size_t)(k0 + row) * Hc + n0 + nq * 4);
        }
        __syncthreads();
#pragma unroll
        for (int k = 0; k < 16; ++k) {
            const float4 a = *(const float4*)&As[k][ty * 4];
            const float4 b = *(const float4*)&Bs[k][tx * 4];
            const float av[4] = {a.x, a.y, a.z, a.w};
            const float bv4[4] = {b.x, b.y, b.z, b.w};
#pragma unroll
            for (int i = 0; i < 4; ++i)
#pragma unroll
                for (int j = 0; j < 4; ++j)
                    acc[i][j] += av[i] * bv4[j];
        }
        __syncthreads();
    }

    const float4 bi = *(const float4*)(bias + n0 + tx * 4);
#pragma unroll
    for (int i = 0; i < 4; ++i) {
        const int m = m0 + ty * 4 + i;
        float4 r;
        r.x = acc[i][0] + bi.x;
        r.y = acc[i][1] + bi.y;
        r.z = acc[i][2] + bi.z;
        r.w = acc[i][3] + bi.w;
        *(float4*)&O[(size_t)m * Hc + n0 + tx * 4] = r;
    }
}

// ---------------------------------------------------------------------------
extern "C" void kernel_launch(void* const* d_in, const int* in_sizes, int n_in,
                              void* d_out, int out_size, void* d_ws, size_t ws_size,
                              hipStream_t stream) {
    (void)in_sizes; (void)n_in; (void)out_size; (void)ws_size;

    const float* X  = (const float*)d_in[0];
    const float* Wq = (const float*)d_in[1];
    const float* bq = (const float*)d_in[2];
    const float* Wk = (const float*)d_in[3];
    const float* bk = (const float*)d_in[4];
    const float* Wv = (const float*)d_in[5];
    const float* bv = (const float*)d_in[6];
    const float* Wo = (const float*)d_in[7];
    const float* bo = (const float*)d_in[8];
    float* out = (float*)d_out;

    float* ws = (float*)d_ws;
    const size_t elems = (size_t)Mc * Hc;   // 8388608
    float* Q  = ws;
    float* K  = Q + elems;
    float* V  = K + elems;
    float* AO = V + elems;                  // total 134.2 MB fp32

    qkv_gemm<<<dim3(96, 64), 256, 0, stream>>>(X, Wq, bq, Wk, bk, Wv, bv, Q, K, V);
    attn_kernel<<<dim3(32, NHc, Bc), 256, 0, stream>>>(Q, K, V, AO);
    out_gemm<<<dim3(32, 64), 256, 0, stream>>>(AO, Wo, bo, out);
}

// Round 2
// 818.119 us; speedup vs baseline: 4.0437x; 4.0437x over previous
//
#include <hip/hip_runtime.h>
#include <hip/hip_bf16.h>
#include <stdint.h>

// MHSA on MI355X: B=2, S=2048, H=2048, NH=16, D=128.
// Round 2: full MFMA pipeline.
//   qkv_gemm : split-bf16 (hi/lo, 3 mfma) fp32->bf16, writes Q,K [b,h,s,d] bf16
//              (Q pre-scaled by 1/sqrt(128)*log2e) and V transposed [b,h,d,s].
//   attn     : flash, plain bf16 MFMA (error budget allows), XOR-swizzled LDS,
//              writes AO as hi/lo bf16 pair.
//   out_gemm : split-bf16 MFMA (AO hi/lo direct, Wo converted on the fly).
// ws: Qd|Kd|Vt|AOhi|AOlo, 5 x 8388608 ushort = 83.9 MB (ws proved >=134 MB).

#define Bc 2
#define Sc 2048
#define Hc 2048
#define NHc 16
#define Dc 128
#define Mc 4096

typedef unsigned short ushortT;
typedef float f32x4 __attribute__((ext_vector_type(4)));
typedef short bf16x8 __attribute__((ext_vector_type(8)));

#define MFMA16(a, b, c) __builtin_amdgcn_mfma_f32_16x16x32_bf16((a), (b), (c), 0, 0, 0)

// fp32 -> bf16 (RNE), returns bits in low 16
static __device__ __forceinline__ uint32_t f2bf(float x) {
    uint32_t b = __float_as_uint(x);
    return (b + 0x7FFFu + ((b >> 16) & 1u)) >> 16;
}
// split-pack a pair: hi word = {bf16hi(x1),bf16hi(x0)}, lo word = residuals
static __device__ __forceinline__ void splitpack(float x0, float x1,
                                                 uint32_t& hi, uint32_t& lo) {
    uint32_t b0 = __float_as_uint(x0), b1 = __float_as_uint(x1);
    uint32_t h0 = b0 & 0xFFFF0000u, h1 = b1 & 0xFFFF0000u;
    hi = (h0 >> 16) | h1;
    lo = f2bf(x0 - __uint_as_float(h0)) | (f2bf(x1 - __uint_as_float(h1)) << 16);
}

// ---------------------------------------------------------------------------
// Fused QKV projection, split-bf16 MFMA. Tile 128x128, BK=32, 4 waves each
// computing a 64x64 quadrant (4x4 frags of 16x16x32).
// grid = (3*16, 32): x = which*16 + n-tile, y = m-tile.
// ---------------------------------------------------------------------------
__global__ __launch_bounds__(256) void qkv_gemm(
    const float* __restrict__ X,
    const float* __restrict__ Wq, const float* __restrict__ bq,
    const float* __restrict__ Wk, const float* __restrict__ bk,
    const float* __restrict__ Wv, const float* __restrict__ bv,
    ushortT* __restrict__ Qd, ushortT* __restrict__ Kd, ushortT* __restrict__ Vt)
{
    const int which = blockIdx.x >> 4;            // 0=Q,1=K,2=V
    const int n0 = (blockIdx.x & 15) * 128;
    const int m0 = blockIdx.y * 128;
    const float* W    = (which == 0) ? Wq : (which == 1) ? Wk : Wv;
    const float* bias = (which == 0) ? bq : (which == 1) ? bk : bv;

    // A as [m][k], B as [n][k]; row stride 40 bf16 (80 B) -> 16B-aligned rows,
    // conflict-free b128 frag reads (odd-ish word stride 20).
    __shared__ ushortT AsHi[128 * 40], AsLo[128 * 40];
    __shared__ ushortT BsHi[128 * 40], BsLo[128 * 40];

    const int tid = threadIdx.x;
    const int wv_ = tid >> 6;
    const int lane = tid & 63;
    const int lane16 = lane & 15;
    const int quad8 = (lane >> 4) * 8;
    const int quad4 = (lane >> 4) * 4;
    const int wm = (wv_ & 1) * 64, wn = (wv_ >> 1) * 64;

    f32x4 acc[4][4];
#pragma unroll
    for (int i = 0; i < 4; ++i)
#pragma unroll
        for (int j = 0; j < 4; ++j) { acc[i][j][0] = 0.f; acc[i][j][1] = 0.f; acc[i][j][2] = 0.f; acc[i][j][3] = 0.f; }

    const int arow = tid >> 1, akh = (tid & 1) * 16;   // A: 2 thr/row, 16 k each
    const int bn = tid & 127, bkh = (tid >> 7) * 16;   // B: thr per n, 16 k each

    for (int k0 = 0; k0 < Hc; k0 += 32) {
        // ---- stage A (X fp32 [m][k], k-contig natural) ----
        {
            float xv[16];
#pragma unroll
            for (int i = 0; i < 4; ++i)
                *(float4*)&xv[i * 4] = *(const float4*)(X + (size_t)(m0 + arow) * Hc + k0 + akh + i * 4);
            uint32_t hi[8], lo[8];
#pragma unroll
            for (int p = 0; p < 8; ++p) splitpack(xv[2 * p], xv[2 * p + 1], hi[p], lo[p]);
            *(uint4*)&AsHi[arow * 40 + akh]     = *(uint4*)&hi[0];
            *(uint4*)&AsHi[arow * 40 + akh + 8] = *(uint4*)&hi[4];
            *(uint4*)&AsLo[arow * 40 + akh]     = *(uint4*)&lo[0];
            *(uint4*)&AsLo[arow * 40 + akh + 8] = *(uint4*)&lo[4];
        }
        // ---- stage B transposed (W fp32 [k][n] -> Bs[n][k]) ----
        {
            float wvv[16];
#pragma unroll
            for (int kk = 0; kk < 16; ++kk)
                wvv[kk] = W[(size_t)(k0 + bkh + kk) * Hc + n0 + bn];  // coalesced across tid
            uint32_t hi[8], lo[8];
#pragma unroll
            for (int p = 0; p < 8; ++p) splitpack(wvv[2 * p], wvv[2 * p + 1], hi[p], lo[p]);
            *(uint4*)&BsHi[bn * 40 + bkh]     = *(uint4*)&hi[0];
            *(uint4*)&BsHi[bn * 40 + bkh + 8] = *(uint4*)&hi[4];
            *(uint4*)&BsLo[bn * 40 + bkh]     = *(uint4*)&lo[0];
            *(uint4*)&BsLo[bn * 40 + bkh + 8] = *(uint4*)&lo[4];
        }
        __syncthreads();

        bf16x8 ah[4], al[4];
#pragma unroll
        for (int mi = 0; mi < 4; ++mi) {
            ah[mi] = *(const bf16x8*)&AsHi[(wm + mi * 16 + lane16) * 40 + quad8];
            al[mi] = *(const bf16x8*)&AsLo[(wm + mi * 16 + lane16) * 40 + quad8];
        }
#pragma unroll
        for (int nj = 0; nj < 4; ++nj) {
            const bf16x8 bh = *(const bf16x8*)&BsHi[(wn + nj * 16 + lane16) * 40 + quad8];
            const bf16x8 bl = *(const bf16x8*)&BsLo[(wn + nj * 16 + lane16) * 40 + quad8];
#pragma unroll
            for (int mi = 0; mi < 4; ++mi) {
                acc[mi][nj] = MFMA16(ah[mi], bh, acc[mi][nj]);
                acc[mi][nj] = MFMA16(ah[mi], bl, acc[mi][nj]);
                acc[mi][nj] = MFMA16(al[mi], bh, acc[mi][nj]);
            }
        }
        __syncthreads();
    }

    // ---- epilogue: bias (+ Q pre-scale incl log2e), bf16, scatter ----
    const float QS = 0.08838834764831845f * 1.4426950408889634f; // 1/sqrt(128)*log2e
#pragma unroll
    for (int nj = 0; nj < 4; ++nj) {
        const int col = n0 + wn + nj * 16 + lane16;
        const float bb = bias[col];
        const int hh = col >> 7, dd = col & 127;
#pragma unroll
        for (int mi = 0; mi < 4; ++mi) {
#pragma unroll
            for (int r = 0; r < 4; ++r) {
                const int m = m0 + wm + mi * 16 + quad4 + r;
                float v = acc[mi][nj][r] + bb;
                const int b = m >> 11, s = m & 2047;
                if (which == 0) {
                    v *= QS;
                    Qd[(((size_t)(b * NHc + hh)) * Sc + s) * Dc + dd] = (ushortT)f2bf(v);
                } else if (which == 1) {
                    Kd[(((size_t)(b * NHc + hh)) * Sc + s) * Dc + dd] = (ushortT)f2bf(v);
                } else {
                    Vt[(((size_t)(b * NHc + hh)) * Dc + dd) * Sc + s] = (ushortT)f2bf(v);
                }
            }
        }
    }
}

// ---------------------------------------------------------------------------
// Flash attention, bf16 MFMA. Block = (128 q-rows) x 4 waves (32-row strips),
// kv-tile 64. Q frags in registers; K/V/P/S in XOR-swizzled LDS.
// grid = (16 qtiles, 16 heads, 2 batch).
// ---------------------------------------------------------------------------
__global__ __launch_bounds__(256) void attn(
    const ushortT* __restrict__ Qd, const ushortT* __restrict__ Kd,
    const ushortT* __restrict__ Vt,
    ushortT* __restrict__ AOhi, ushortT* __restrict__ AOlo)
{
    const int qt = blockIdx.x, hh = blockIdx.y, bb = blockIdx.z;
    const ushortT* Qp = Qd + ((size_t)(bb * NHc + hh)) * Sc * Dc;
    const ushortT* Kp = Kd + ((size_t)(bb * NHc + hh)) * Sc * Dc;
    const ushortT* Vp = Vt + ((size_t)(bb * NHc + hh)) * Dc * Sc;

    __shared__ ushortT Ks[64 * 128];   // [skv][d], granule-swizzled
    __shared__ ushortT Vs[128 * 64];   // [d][skv], granule-swizzled
    __shared__ float   SsF[4 * 32 * 64]; // per-wave: S fp32 then reused as P bf16
    __shared__ float   alphas[4 * 32], linvs[4 * 32];

    const int tid = threadIdx.x, wv_ = tid >> 6, lane = tid & 63;
    const int lane16 = lane & 15, quad = lane >> 4;
    const int quad8 = quad * 8, quad4 = quad * 4;
    const int s0 = qt * 128 + wv_ * 32;

    // Q fragments resident in registers (pre-scaled in qkv epilogue)
    bf16x8 q[2][4];
#pragma unroll
    for (int mi = 0; mi < 2; ++mi)
#pragma unroll
        for (int kf = 0; kf < 4; ++kf)
            q[mi][kf] = *(const bf16x8*)(Qp + (size_t)(s0 + mi * 16 + lane16) * Dc + kf * 32 + quad8);

    f32x4 o[2][8];
#pragma unroll
    for (int mi = 0; mi < 2; ++mi)
#pragma unroll
        for (int dj = 0; dj < 8; ++dj) { o[mi][dj][0] = 0.f; o[mi][dj][1] = 0.f; o[mi][dj][2] = 0.f; o[mi][dj][3] = 0.f; }

    float m_run = -1e30f, l_run = 0.f;
    const int sr = lane >> 1, sch = (lane & 1) * 32;   // softmax: lane -> (row, col-half)
    const int kr = tid >> 2, kseg = tid & 3;           // K staging
    const int vr = tid >> 1, vseg = tid & 1;           // V staging
    float* Sw = &SsF[wv_ * 2048];
    ushortT* Pw = (ushortT*)Sw;

    for (int nt = 0; nt < 32; ++nt) {
        // ---- stage K tile [64][128] and V tile [128][64] (swizzled) ----
        const ushortT* ksrc = Kp + (size_t)(nt * 64 + kr) * Dc + kseg * 32;
#pragma unroll
        for (int i = 0; i < 4; ++i)
            *(uint4*)&Ks[kr * 128 + (((kseg * 4 + i) ^ (kr & 7)) << 3)] = *(const uint4*)(ksrc + i * 8);
        const ushortT* vsrc = Vp + (size_t)vr * Sc + nt * 64 + vseg * 32;
#pragma unroll
        for (int i = 0; i < 4; ++i)
            *(uint4*)&Vs[vr * 64 + (((vseg * 4 + i) ^ (vr & 7)) << 3)] = *(const uint4*)(vsrc + i * 8);
        __syncthreads();

        // ---- S = Q K^T (strip 32 x 64) ----
        f32x4 sacc[2][4];
#pragma unroll
        for (int mi = 0; mi < 2; ++mi)
#pragma unroll
            for (int nj = 0; nj < 4; ++nj) { sacc[mi][nj][0] = 0.f; sacc[mi][nj][1] = 0.f; sacc[mi][nj][2] = 0.f; sacc[mi][nj][3] = 0.f; }
#pragma unroll
        for (int kf = 0; kf < 4; ++kf) {
            bf16x8 kb[4];
#pragma unroll
            for (int nj = 0; nj < 4; ++nj) {
                const int row = nj * 16 + lane16;
                kb[nj] = *(const bf16x8*)&Ks[row * 128 + (((kf * 4 + quad) ^ (row & 7)) << 3)];
            }
#pragma unroll
            for (int mi = 0; mi < 2; ++mi)
#pragma unroll
                for (int nj = 0; nj < 4; ++nj)
                    sacc[mi][nj] = MFMA16(q[mi][kf], kb[nj], sacc[mi][nj]);
        }
        // ---- spill S to wave-private LDS (fp32, swizzled) ----
#pragma unroll
        for (int mi = 0; mi < 2; ++mi)
#pragma unroll
            for (int nj = 0; nj < 4; ++nj)
#pragma unroll
                for (int r = 0; r < 4; ++r) {
                    const int row = mi * 16 + quad4 + r, col = nj * 16 + lane16;
                    Sw[row * 64 + (((col >> 2) ^ (row & 15)) << 2) + (col & 3)] = sacc[mi][nj][r];
                }
        // ---- online softmax: lane owns (row=lane/2, 32-col half) ----
        float svv[32];
#pragma unroll
        for (int i = 0; i < 8; ++i)
            *(float4*)&svv[i * 4] = *(const float4*)&Sw[sr * 64 + ((((sch >> 2) + i) ^ (sr & 15)) << 2)];
        float mx = svv[0];
#pragma unroll
        for (int i = 1; i < 32; ++i) mx = fmaxf(mx, svv[i]);
        mx = fmaxf(mx, __shfl_xor(mx, 1));
        const float mnew = fmaxf(m_run, mx);
        const float alpha = exp2f(m_run - mnew);
        m_run = mnew;
        float sum = 0.f;
#pragma unroll
        for (int i = 0; i < 32; ++i) { const float p = exp2f(svv[i] - mnew); svv[i] = p; sum += p; }
        sum += __shfl_xor(sum, 1);
        l_run = l_run * alpha + sum;
        if (!(lane & 1)) alphas[wv_ * 32 + sr] = alpha;
        // P -> bf16 into same wave-private region (all S reads already done)
        uint32_t pu[16];
#pragma unroll
        for (int i = 0; i < 16; ++i) pu[i] = f2bf(svv[2 * i]) | (f2bf(svv[2 * i + 1]) << 16);
#pragma unroll
        for (int i = 0; i < 4; ++i)
            *(uint4*)&Pw[sr * 64 + ((((sch >> 3) + i) ^ (sr & 7)) << 3)] = *(uint4*)&pu[i * 4];
        // ---- rescale O ----
#pragma unroll
        for (int mi = 0; mi < 2; ++mi)
#pragma unroll
            for (int r = 0; r < 4; ++r) {
                const int row = mi * 16 + quad4 + r;
                const float av = alphas[wv_ * 32 + row];
#pragma unroll
                for (int dj = 0; dj < 8; ++dj) o[mi][dj][r] *= av;
            }
        // ---- O += P V ----
#pragma unroll
        for (int kf2 = 0; kf2 < 2; ++kf2) {
            bf16x8 pa[2];
#pragma unroll
            for (int mi = 0; mi < 2; ++mi) {
                const int row = mi * 16 + lane16;
                pa[mi] = *(const bf16x8*)&Pw[row * 64 + (((kf2 * 4 + quad) ^ (row & 7)) << 3)];
            }
#pragma unroll
            for (int dj = 0; dj < 8; ++dj) {
                const int row = dj * 16 + lane16;
                const bf16x8 vb = *(const bf16x8*)&Vs[row * 64 + (((kf2 * 4 + quad) ^ (row & 7)) << 3)];
#pragma unroll
                for (int mi = 0; mi < 2; ++mi)
                    o[mi][dj] = MFMA16(pa[mi], vb, o[mi][dj]);
            }
        }
        __syncthreads();
    }

    // ---- epilogue: /l, split to hi/lo bf16, write AO[m][h*128+d] ----
    if (!(lane & 1)) linvs[wv_ * 32 + sr] = 1.f / l_run;
#pragma unroll
    for (int mi = 0; mi < 2; ++mi)
#pragma unroll
        for (int r = 0; r < 4; ++r) {
            const int row = mi * 16 + quad4 + r;
            const float li = linvs[wv_ * 32 + row];
            const size_t base = ((size_t)(bb * Sc + qt * 128 + wv_ * 32 + row)) * Hc + hh * Dc;
#pragma unroll
            for (int dj = 0; dj < 8; ++dj) {
                const int d = dj * 16 + lane16;
                const float v = o[mi][dj][r] * li;
                const uint32_t bv_ = __float_as_uint(v), hb = bv_ & 0xFFFF0000u;
                AOhi[base + d] = (ushortT)(hb >> 16);
                AOlo[base + d] = (ushortT)f2bf(v - __uint_as_float(hb));
            }
        }
}

// ---------------------------------------------------------------------------
// Output projection: out = AO @ Wo + bo, split-bf16 MFMA (AO already hi/lo).
// grid = (16, 32).
// ---------------------------------------------------------------------------
__global__ __launch_bounds__(256) void out_gemm(
    const ushortT* __restrict__ AOhi, const ushortT* __restrict__ AOlo,
    const float* __restrict__ W, const float* __restrict__ bo,
    float* __restrict__ out)
{
    const int n0 = blockIdx.x * 128;
    const int m0 = blockIdx.y * 128;

    __shared__ ushortT AsHi[128 * 40], AsLo[128 * 40];
    __shared__ ushortT BsHi[128 * 40], BsLo[128 * 40];

    const int tid = threadIdx.x;
    const int wv_ = tid >> 6;
    const int lane = tid & 63;
    const int lane16 = lane & 15;
    const int quad8 = (lane >> 4) * 8;
    const int quad4 = (lane >> 4) * 4;
    const int wm = (wv_ & 1) * 64, wn = (wv_ >> 1) * 64;

    f32x4 acc[4][4];
#pragma unroll
    for (int i = 0; i < 4; ++i)
#pragma unroll
        for (int j = 0; j < 4; ++j) { acc[i][j][0] = 0.f; acc[i][j][1] = 0.f; acc[i][j][2] = 0.f; acc[i][j][3] = 0.f; }

    const int arow = tid >> 1, akh = (tid & 1) * 16;
    const int bn = tid & 127, bkh = (tid >> 7) * 16;

    for (int k0 = 0; k0 < Hc; k0 += 32) {
        // A: AO already split bf16 — straight copy
        *(uint4*)&AsHi[arow * 40 + akh]     = *(const uint4*)(AOhi + (size_t)(m0 + arow) * Hc + k0 + akh);
        *(uint4*)&AsHi[arow * 40 + akh + 8] = *(const uint4*)(AOhi + (size_t)(m0 + arow) * Hc + k0 + akh + 8);
        *(uint4*)&AsLo[arow * 40 + akh]     = *(const uint4*)(AOlo + (size_t)(m0 + arow) * Hc + k0 + akh);
        *(uint4*)&AsLo[arow * 40 + akh + 8] = *(const uint4*)(AOlo + (size_t)(m0 + arow) * Hc + k0 + akh + 8);
        // B: Wo fp32 [k][n] -> Bs[n][k] split
        {
            float wvv[16];
#pragma unroll
            for (int kk = 0; kk < 16; ++kk)
                wvv[kk] = W[(size_t)(k0 + bkh + kk) * Hc + n0 + bn];
            uint32_t hi[8], lo[8];
#pragma unroll
            for (int p = 0; p < 8; ++p) splitpack(wvv[2 * p], wvv[2 * p + 1], hi[p], lo[p]);
            *(uint4*)&BsHi[bn * 40 + bkh]     = *(uint4*)&hi[0];
            *(uint4*)&BsHi[bn * 40 + bkh + 8] = *(uint4*)&hi[4];
            *(uint4*)&BsLo[bn * 40 + bkh]     = *(uint4*)&lo[0];
            *(uint4*)&BsLo[bn * 40 + bkh + 8] = *(uint4*)&lo[4];
        }
        __syncthreads();

        bf16x8 ah[4], al[4];
#pragma unroll
        for (int mi = 0; mi < 4; ++mi) {
            ah[mi] = *(const bf16x8*)&AsHi[(wm + mi * 16 + lane16) * 40 + quad8];
            al[mi] = *(const bf16x8*)&AsLo[(wm + mi * 16 + lane16) * 40 + quad8];
        }
#pragma unroll
        for (int nj = 0; nj < 4; ++nj) {
            const bf16x8 bh = *(const bf16x8*)&BsHi[(wn + nj * 16 + lane16) * 40 + quad8];
            const bf16x8 bl = *(const bf16x8*)&BsLo[(wn + nj * 16 + lane16) * 40 + quad8];
#pragma unroll
            for (int mi = 0; mi < 4; ++mi) {
                acc[mi][nj] = MFMA16(ah[mi], bh, acc[mi][nj]);
                acc[mi][nj] = MFMA16(ah[mi], bl, acc[mi][nj]);
                acc[mi][nj] = MFMA16(al[mi], bh, acc[mi][nj]);
            }
        }
        __syncthreads();
    }

#pragma unroll
    for (int nj = 0; nj < 4; ++nj) {
        const int col = n0 + wn + nj * 16 + lane16;
        const float bb = bo[col];
#pragma unroll
        for (int mi = 0; mi < 4; ++mi)
#pragma unroll
            for (int r = 0; r < 4; ++r) {
                const int m = m0 + wm + mi * 16 + quad4 + r;
                out[(size_t)m * Hc + col] = acc[mi][nj][r] + bb;
            }
    }
}

// ---------------------------------------------------------------------------
extern "C" void kernel_launch(void* const* d_in, const int* in_sizes, int n_in,
                              void* d_out, int out_size, void* d_ws, size_t ws_size,
                              hipStream_t stream) {
    (void)in_sizes; (void)n_in; (void)out_size; (void)ws_size;

    const float* X  = (const float*)d_in[0];
    const float* Wq = (const float*)d_in[1];
    const float* bq = (const float*)d_in[2];
    const float* Wk = (const float*)d_in[3];
    const float* bk = (const float*)d_in[4];
    const float* Wv = (const float*)d_in[5];
    const float* bv = (const float*)d_in[6];
    const float* Wo = (const float*)d_in[7];
    const float* bo = (const float*)d_in[8];
    float* out = (float*)d_out;

    ushortT* ws = (ushortT*)d_ws;
    const size_t E = (size_t)Mc * Hc;   // 8388608
    ushortT* Qd   = ws;
    ushortT* Kd   = Qd + E;
    ushortT* Vt   = Kd + E;
    ushortT* AOhi = Vt + E;
    ushortT* AOlo = AOhi + E;           // total 83.9 MB

    qkv_gemm<<<dim3(48, 32), 256, 0, stream>>>(X, Wq, bq, Wk, bk, Wv, bv, Qd, Kd, Vt);
    attn<<<dim3(16, NHc, Bc), 256, 0, stream>>>(Qd, Kd, Vt, AOhi, AOlo);
    out_gemm<<<dim3(16, 32), 256, 0, stream>>>(AOhi, AOlo, Wo, bo, out);
}

// Round 3
// 523.006 us; speedup vs baseline: 6.3254x; 1.5643x over previous
//
#include <hip/hip_runtime.h>
#include <hip/hip_bf16.h>
#include <stdint.h>

// MHSA on MI355X: B=2, S=2048, H=2048, NH=16, D=128. Round 3: all-fp16 MFMA.
//   pack_a  : X fp32 -> Xp fp16, tile-blocked [mt][kt][128 rows][8 granules
//             XOR-swizzled][8 fp16] (tile = exact LDS image, 16 KB).
//   pack_b  : W fp32 [k][n] -> Wp fp16 B-operand layout [nt][kt][n-row][g][8].
//   qkv_gemm: 128x128 tile, BK=64, global_load_lds(16B) staging, 1 f16 MFMA
//             per frag (no split needed: fp16 eps ~1.6e-4 -> out err ~4e-4).
//   attn    : round-2 flash structure, f16 MFMA, writes AO in packed A layout.
//   out_gemm: same GEMM skeleton, fp32 epilogue.
// ws: Xp | Wqp Wkp Wvp Wop | Qd Kd Vt | AOp = 117.4 MB (<134 MB proven).

#define Bc 2
#define Sc 2048
#define Hc 2048
#define NHc 16
#define Dc 128
#define Mc 4096

typedef unsigned short ushortT;
typedef float f32x4 __attribute__((ext_vector_type(4)));
typedef _Float16 f16x8 __attribute__((ext_vector_type(8)));

#define MFMAH(a, b, c) __builtin_amdgcn_mfma_f32_16x16x32_f16((a), (b), (c), 0, 0, 0)

static __device__ __forceinline__ ushortT f2h(float x) {
    _Float16 h = (_Float16)x;
    return __builtin_bit_cast(unsigned short, h);
}

// async global->LDS, 16 B per lane; dest must be wave-uniform base (+lane*16)
static __device__ __forceinline__ void load_lds16(const ushortT* g, ushortT* l) {
    __builtin_amdgcn_global_load_lds(
        (__attribute__((address_space(1))) void*)(g),
        (__attribute__((address_space(3))) void*)(l), 16, 0, 0);
}

// ---------------------------------------------------------------------------
// pack_a: X [4096][2048] fp32 -> Xp tiled fp16. grid (32 mt, 32 kt) x 256.
// Tile image: row r (128), granule g (8 fp16), physical g' = g ^ (r&7).
// ---------------------------------------------------------------------------
__global__ __launch_bounds__(256) void pack_a(
    const float* __restrict__ src, ushortT* __restrict__ dst)
{
    const int mt = blockIdx.x, kt = blockIdx.y;
    const int t = threadIdx.x;
    const int kq = t & 15;        // float4 index within 64-k span
    const int r0 = t >> 4;        // 16 row-groups, 8 rows each
    ushortT* tile = dst + ((size_t)(mt * 32 + kt)) * 8192;
#pragma unroll
    for (int rr = 0; rr < 8; ++rr) {
        const int row = r0 + rr * 16;
        const float4 v = *(const float4*)(src + (size_t)(mt * 128 + row) * Hc + kt * 64 + kq * 4);
        _Float16 h[4] = {(_Float16)v.x, (_Float16)v.y, (_Float16)v.z, (_Float16)v.w};
        const int gid = kq >> 1, halfg = kq & 1;
        const int gp = gid ^ (row & 7);
        *(uint2*)(tile + (size_t)row * 64 + gp * 8 + halfg * 4) = *(uint2*)h;
    }
}

// ---------------------------------------------------------------------------
// pack_b: W [2048 k][2048 n] fp32 -> B-operand tiled fp16 (element (n,k)).
// grid (16 nt, 32 kt, 4 which) x 256.
// ---------------------------------------------------------------------------
__global__ __launch_bounds__(256) void pack_b(
    const float* __restrict__ W0, const float* __restrict__ W1,
    const float* __restrict__ W2, const float* __restrict__ W3,
    ushortT* __restrict__ dst)   // 4 weights contiguous, 4194304 ushorts each
{
    const int nt = blockIdx.x, kt = blockIdx.y, which = blockIdx.z;
    const float* W = (which == 0) ? W0 : (which == 1) ? W1 : (which == 2) ? W2 : W3;
    const int t = threadIdx.x;
    const int n = t & 127;
    const int g0 = (t >> 7) * 4;
    ushortT* tile = dst + (size_t)which * 4194304 + ((size_t)(nt * 32 + kt)) * 8192;
#pragma unroll
    for (int gi = 0; gi < 4; ++gi) {
        const int g = g0 + gi;
        _Float16 h[8];
#pragma unroll
        for (int j = 0; j < 8; ++j)
            h[j] = (_Float16)W[(size_t)(kt * 64 + g * 8 + j) * Hc + nt * 128 + n];
        const int gp = g ^ (n & 7);
        *(uint4*)(tile + (size_t)n * 64 + gp * 8) = *(uint4*)h;
    }
}

// ---------------------------------------------------------------------------
// GEMM core macros: 128x128 tile, BK=64, 4 waves x (64x64 quadrant, 4x4 frags)
// ---------------------------------------------------------------------------
#define GEMM_PROLOGUE()                                                        \
    __shared__ __align__(16) ushortT As[8192], Bs[8192];                       \
    const int tid = threadIdx.x, wv_ = tid >> 6, lane = tid & 63;              \
    const int lane16 = lane & 15, quad = lane >> 4;                            \
    const int quad4 = quad * 4;                                                \
    const int wm = (wv_ & 1) * 64, wn = (wv_ >> 1) * 64;                       \
    int aoff[4][2], boff[4][2];                                                \
    _Pragma("unroll") for (int mi = 0; mi < 4; ++mi)                           \
        _Pragma("unroll") for (int kf = 0; kf < 2; ++kf) {                     \
            const int ra = wm + mi * 16 + lane16;                              \
            aoff[mi][kf] = ra * 64 + (((kf * 4 + quad) ^ (ra & 7)) << 3);      \
            const int rb = wn + mi * 16 + lane16;                              \
            boff[mi][kf] = rb * 64 + (((kf * 4 + quad) ^ (rb & 7)) << 3);      \
        }                                                                      \
    f32x4 acc[4][4];                                                           \
    _Pragma("unroll") for (int i = 0; i < 4; ++i)                              \
        _Pragma("unroll") for (int j = 0; j < 4; ++j) {                        \
            acc[i][j][0] = 0.f; acc[i][j][1] = 0.f;                            \
            acc[i][j][2] = 0.f; acc[i][j][3] = 0.f; }                          \
    ushortT* asd = &As[wv_ * 2048];                                            \
    ushortT* bsd = &Bs[wv_ * 2048];

#define GEMM_KLOOP(at, bt)                                                     \
    for (int kt2 = 0; kt2 < 32; ++kt2) {                                       \
        _Pragma("unroll") for (int i = 0; i < 4; ++i) {                        \
            load_lds16(at + i * 512 + lane * 8, asd + i * 512);                \
            load_lds16(bt + i * 512 + lane * 8, bsd + i * 512);                \
        }                                                                      \
        at += 8192; bt += 8192;                                                \
        __syncthreads();                                                       \
        _Pragma("unroll") for (int kf = 0; kf < 2; ++kf) {                     \
            f16x8 a[4], b[4];                                                  \
            _Pragma("unroll") for (int mi = 0; mi < 4; ++mi)                   \
                a[mi] = *(const f16x8*)&As[aoff[mi][kf]];                      \
            _Pragma("unroll") for (int nj = 0; nj < 4; ++nj)                   \
                b[nj] = *(const f16x8*)&Bs[boff[nj][kf]];                      \
            _Pragma("unroll") for (int nj = 0; nj < 4; ++nj)                   \
                _Pragma("unroll") for (int mi = 0; mi < 4; ++mi)               \
                    acc[mi][nj] = MFMAH(a[mi], b[nj], acc[mi][nj]);            \
        }                                                                      \
        __syncthreads();                                                       \
    }

// ---------------------------------------------------------------------------
// Fused QKV projection. grid = (48, 32): x = which*16 + ntile, y = mtile.
// ---------------------------------------------------------------------------
__global__ __launch_bounds__(256) void qkv_gemm(
    const ushortT* __restrict__ Xp, const ushortT* __restrict__ Wall,
    const float* __restrict__ bq, const float* __restrict__ bk,
    const float* __restrict__ bv,
    ushortT* __restrict__ Qd, ushortT* __restrict__ Kd, ushortT* __restrict__ Vt)
{
    const int which = blockIdx.x >> 4;
    const int nt = blockIdx.x & 15;
    const int mt = blockIdx.y;
    const ushortT* Wp = Wall + (size_t)which * 4194304;
    const float* bias = (which == 0) ? bq : (which == 1) ? bk : bv;

    GEMM_PROLOGUE();

    const ushortT* at = Xp + (size_t)(mt * 32) * 8192 + wv_ * 2048;
    const ushortT* bt = Wp + (size_t)(nt * 32) * 8192 + wv_ * 2048;
    GEMM_KLOOP(at, bt);

    // epilogue: bias (+ Q pre-scale incl log2e), fp16, scatter
    const float QS = 0.08838834764831845f * 1.4426950408889634f;
#pragma unroll
    for (int nj = 0; nj < 4; ++nj) {
        const int col = nt * 128 + wn + nj * 16 + lane16;
        const float bb = bias[col];
        const int hh = col >> 7, dd = col & 127;
#pragma unroll
        for (int mi = 0; mi < 4; ++mi)
#pragma unroll
            for (int r = 0; r < 4; ++r) {
                const int m = mt * 128 + wm + mi * 16 + quad4 + r;
                const int b = m >> 11, s = m & 2047;
                float v = acc[mi][nj][r] + bb;
                if (which == 0)
                    Qd[(((size_t)(b * NHc + hh)) * Sc + s) * Dc + dd] = f2h(v * QS);
                else if (which == 1)
                    Kd[(((size_t)(b * NHc + hh)) * Sc + s) * Dc + dd] = f2h(v);
                else
                    Vt[(((size_t)(b * NHc + hh)) * Dc + dd) * Sc + s] = f2h(v);
            }
    }
}

// ---------------------------------------------------------------------------
// Flash attention, f16 MFMA (round-2 structure). grid = (16, 16, 2).
// Epilogue writes AO directly in packed A-operand layout for out_gemm.
// ---------------------------------------------------------------------------
__global__ __launch_bounds__(256) void attn(
    const ushortT* __restrict__ Qd, const ushortT* __restrict__ Kd,
    const ushortT* __restrict__ Vt, ushortT* __restrict__ AOp)
{
    const int qt = blockIdx.x, hh = blockIdx.y, bb = blockIdx.z;
    const ushortT* Qp = Qd + ((size_t)(bb * NHc + hh)) * Sc * Dc;
    const ushortT* Kp = Kd + ((size_t)(bb * NHc + hh)) * Sc * Dc;
    const ushortT* Vp = Vt + ((size_t)(bb * NHc + hh)) * Dc * Sc;

    __shared__ __align__(16) ushortT Ks[64 * 128];
    __shared__ __align__(16) ushortT Vs[128 * 64];
    __shared__ __align__(16) float   SsF[4 * 32 * 64];
    __shared__ float alphas[4 * 32], linvs[4 * 32];

    const int tid = threadIdx.x, wv_ = tid >> 6, lane = tid & 63;
    const int lane16 = lane & 15, quad = lane >> 4;
    const int quad8 = quad * 8, quad4 = quad * 4;
    const int s0 = qt * 128 + wv_ * 32;

    f16x8 q[2][4];
#pragma unroll
    for (int mi = 0; mi < 2; ++mi)
#pragma unroll
        for (int kf = 0; kf < 4; ++kf)
            q[mi][kf] = *(const f16x8*)(Qp + (size_t)(s0 + mi * 16 + lane16) * Dc + kf * 32 + quad8);

    f32x4 o[2][8];
#pragma unroll
    for (int mi = 0; mi < 2; ++mi)
#pragma unroll
        for (int dj = 0; dj < 8; ++dj) { o[mi][dj][0] = 0.f; o[mi][dj][1] = 0.f; o[mi][dj][2] = 0.f; o[mi][dj][3] = 0.f; }

    float m_run = -1e30f, l_run = 0.f;
    const int sr = lane >> 1, sch = (lane & 1) * 32;
    const int kr = tid >> 2, kseg = tid & 3;
    const int vr = tid >> 1, vseg = tid & 1;
    float* Sw = &SsF[wv_ * 2048];
    ushortT* Pw = (ushortT*)Sw;

    for (int nt = 0; nt < 32; ++nt) {
        const ushortT* ksrc = Kp + (size_t)(nt * 64 + kr) * Dc + kseg * 32;
#pragma unroll
        for (int i = 0; i < 4; ++i)
            *(uint4*)&Ks[kr * 128 + (((kseg * 4 + i) ^ (kr & 7)) << 3)] = *(const uint4*)(ksrc + i * 8);
        const ushortT* vsrc = Vp + (size_t)vr * Sc + nt * 64 + vseg * 32;
#pragma unroll
        for (int i = 0; i < 4; ++i)
            *(uint4*)&Vs[vr * 64 + (((vseg * 4 + i) ^ (vr & 7)) << 3)] = *(const uint4*)(vsrc + i * 8);
        __syncthreads();

        // S = Q K^T
        f32x4 sacc[2][4];
#pragma unroll
        for (int mi = 0; mi < 2; ++mi)
#pragma unroll
            for (int nj = 0; nj < 4; ++nj) { sacc[mi][nj][0] = 0.f; sacc[mi][nj][1] = 0.f; sacc[mi][nj][2] = 0.f; sacc[mi][nj][3] = 0.f; }
#pragma unroll
        for (int kf = 0; kf < 4; ++kf) {
            f16x8 kb[4];
#pragma unroll
            for (int nj = 0; nj < 4; ++nj) {
                const int row = nj * 16 + lane16;
                kb[nj] = *(const f16x8*)&Ks[row * 128 + (((kf * 4 + quad) ^ (row & 7)) << 3)];
            }
#pragma unroll
            for (int mi = 0; mi < 2; ++mi)
#pragma unroll
                for (int nj = 0; nj < 4; ++nj)
                    sacc[mi][nj] = MFMAH(q[mi][kf], kb[nj], sacc[mi][nj]);
        }
        // spill S (fp32, swizzled)
#pragma unroll
        for (int mi = 0; mi < 2; ++mi)
#pragma unroll
            for (int nj = 0; nj < 4; ++nj)
#pragma unroll
                for (int r = 0; r < 4; ++r) {
                    const int row = mi * 16 + quad4 + r, col = nj * 16 + lane16;
                    Sw[row * 64 + (((col >> 2) ^ (row & 15)) << 2) + (col & 3)] = sacc[mi][nj][r];
                }
        // online softmax (lane owns row=lane/2, 32-col half)
        float svv[32];
#pragma unroll
        for (int i = 0; i < 8; ++i)
            *(float4*)&svv[i * 4] = *(const float4*)&Sw[sr * 64 + ((((sch >> 2) + i) ^ (sr & 15)) << 2)];
        float mx = svv[0];
#pragma unroll
        for (int i = 1; i < 32; ++i) mx = fmaxf(mx, svv[i]);
        mx = fmaxf(mx, __shfl_xor(mx, 1));
        const float mnew = fmaxf(m_run, mx);
        const float alpha = exp2f(m_run - mnew);
        m_run = mnew;
        float sum = 0.f;
#pragma unroll
        for (int i = 0; i < 32; ++i) { const float p = exp2f(svv[i] - mnew); svv[i] = p; sum += p; }
        sum += __shfl_xor(sum, 1);
        l_run = l_run * alpha + sum;
        if (!(lane & 1)) alphas[wv_ * 32 + sr] = alpha;
        // P -> fp16
        uint32_t pu[16];
#pragma unroll
        for (int i = 0; i < 16; ++i)
            pu[i] = (uint32_t)f2h(svv[2 * i]) | ((uint32_t)f2h(svv[2 * i + 1]) << 16);
#pragma unroll
        for (int i = 0; i < 4; ++i)
            *(uint4*)&Pw[sr * 64 + ((((sch >> 3) + i) ^ (sr & 7)) << 3)] = *(uint4*)&pu[i * 4];
        // rescale O
#pragma unroll
        for (int mi = 0; mi < 2; ++mi)
#pragma unroll
            for (int r = 0; r < 4; ++r) {
                const int row = mi * 16 + quad4 + r;
                const float av = alphas[wv_ * 32 + row];
#pragma unroll
                for (int dj = 0; dj < 8; ++dj) o[mi][dj][r] *= av;
            }
        // O += P V
#pragma unroll
        for (int kf2 = 0; kf2 < 2; ++kf2) {
            f16x8 pa[2];
#pragma unroll
            for (int mi = 0; mi < 2; ++mi) {
                const int row = mi * 16 + lane16;
                pa[mi] = *(const f16x8*)&Pw[row * 64 + (((kf2 * 4 + quad) ^ (row & 7)) << 3)];
            }
#pragma unroll
            for (int dj = 0; dj < 8; ++dj) {
                const int row = dj * 16 + lane16;
                const f16x8 vb = *(const f16x8*)&Vs[row * 64 + (((kf2 * 4 + quad) ^ (row & 7)) << 3)];
#pragma unroll
                for (int mi = 0; mi < 2; ++mi)
                    o[mi][dj] = MFMAH(pa[mi], vb, o[mi][dj]);
            }
        }
        __syncthreads();
    }

    // epilogue: /l, write AO in packed tiled-swizzled A layout
    if (!(lane & 1)) linvs[wv_ * 32 + sr] = 1.f / l_run;
#pragma unroll
    for (int mi = 0; mi < 2; ++mi)
#pragma unroll
        for (int r = 0; r < 4; ++r) {
            const int row = mi * 16 + quad4 + r;
            const float li = linvs[wv_ * 32 + row];
            const int mrow = bb * Sc + qt * 128 + wv_ * 32 + row;
            const int mtile = mrow >> 7, rin = mrow & 127;
#pragma unroll
            for (int dj = 0; dj < 8; ++dj) {
                const int kt = hh * 2 + (dj >> 2);
                const int colin = (dj & 3) * 16 + lane16;
                const int g = colin >> 3, e = colin & 7;
                const int gp = g ^ (rin & 7);
                AOp[((size_t)(mtile * 32 + kt)) * 8192 + rin * 64 + gp * 8 + e] =
                    f2h(o[mi][dj][r] * li);
            }
        }
}

// ---------------------------------------------------------------------------
// Output projection: out = AO @ Wo + bo, fp16 MFMA. grid = (16, 32).
// ---------------------------------------------------------------------------
__global__ __launch_bounds__(256) void out_gemm(
    const ushortT* __restrict__ AOp, const ushortT* __restrict__ Wop,
    const float* __restrict__ bo, float* __restrict__ out)
{
    const int nt = blockIdx.x;
    const int mt = blockIdx.y;

    GEMM_PROLOGUE();

    const ushortT* at = AOp + (size_t)(mt * 32) * 8192 + wv_ * 2048;
    const ushortT* bt = Wop + (size_t)(nt * 32) * 8192 + wv_ * 2048;
    GEMM_KLOOP(at, bt);

#pragma unroll
    for (int nj = 0; nj < 4; ++nj) {
        const int col = nt * 128 + wn + nj * 16 + lane16;
        const float bb = bo[col];
#pragma unroll
        for (int mi = 0; mi < 4; ++mi)
#pragma unroll
            for (int r = 0; r < 4; ++r) {
                const int m = mt * 128 + wm + mi * 16 + quad4 + r;
                out[(size_t)m * Hc + col] = acc[mi][nj][r] + bb;
            }
    }
}

// ---------------------------------------------------------------------------
extern "C" void kernel_launch(void* const* d_in, const int* in_sizes, int n_in,
                              void* d_out, int out_size, void* d_ws, size_t ws_size,
                              hipStream_t stream) {
    (void)in_sizes; (void)n_in; (void)out_size; (void)ws_size;

    const float* X  = (const float*)d_in[0];
    const float* Wq = (const float*)d_in[1];
    const float* bq = (const float*)d_in[2];
    const float* Wk = (const float*)d_in[3];
    const float* bk = (const float*)d_in[4];
    const float* Wv = (const float*)d_in[5];
    const float* bv = (const float*)d_in[6];
    const float* Wo = (const float*)d_in[7];
    const float* bo = (const float*)d_in[8];
    float* out = (float*)d_out;

    ushortT* ws = (ushortT*)d_ws;
    const size_t E = (size_t)Mc * Hc;      // 8388608
    const size_t WE = (size_t)Hc * Hc;     // 4194304
    ushortT* Xp   = ws;
    ushortT* Wall = Xp + E;                // Wq|Wk|Wv|Wo packed, contiguous
    ushortT* Qd   = Wall + 4 * WE;
    ushortT* Kd   = Qd + E;
    ushortT* Vt   = Kd + E;
    ushortT* AOp  = Vt + E;                // total 117.4 MB

    pack_a<<<dim3(32, 32), 256, 0, stream>>>(X, Xp);
    pack_b<<<dim3(16, 32, 4), 256, 0, stream>>>(Wq, Wk, Wv, Wo, Wall);
    qkv_gemm<<<dim3(48, 32), 256, 0, stream>>>(Xp, Wall, bq, bk, bv, Qd, Kd, Vt);
    attn<<<dim3(16, NHc, Bc), 256, 0, stream>>>(Qd, Kd, Vt, AOp);
    out_gemm<<<dim3(16, 32), 256, 0, stream>>>(AOp, Wall + 3 * WE, bo, out);
}

// Round 4
// 452.924 us; speedup vs baseline: 7.3042x; 1.1547x over previous
//
#include <hip/hip_runtime.h>
#include <hip/hip_bf16.h>
#include <stdint.h>

// MHSA on MI355X: B=2, S=2048, H=2048, NH=16, D=128. Round 4.
//   pack_a/pack_b : unchanged (fp32 -> fp16 tiled LDS images).
//   qkv_gemm      : unchanged core; K and V epilogues now write the EXACT
//                   attn LDS tile image (64x128 / 128x64, granule-swizzled)
//                   so attn can stage via global_load_lds DMA.
//   attn          : K/V staged with global_load_lds(16B) (no staging VALU),
//                   chunked softmax (16-row chunks, stride-68 S buffer),
//                   vectorized P writes, V-frags register-cached.
//   out_gemm      : unchanged.
// ws: Xp | Wq..Wo | Qd Kd Vt | AOp = 117.4 MB.

#define Bc 2
#define Sc 2048
#define Hc 2048
#define NHc 16
#define Dc 128
#define Mc 4096

typedef unsigned short ushortT;
typedef float f32x4 __attribute__((ext_vector_type(4)));
typedef _Float16 f16x8 __attribute__((ext_vector_type(8)));

#define MFMAH(a, b, c) __builtin_amdgcn_mfma_f32_16x16x32_f16((a), (b), (c), 0, 0, 0)

static __device__ __forceinline__ ushortT f2h(float x) {
    _Float16 h = (_Float16)x;
    return __builtin_bit_cast(unsigned short, h);
}

static __device__ __forceinline__ void load_lds16(const ushortT* g, ushortT* l) {
    __builtin_amdgcn_global_load_lds(
        (__attribute__((address_space(1))) void*)(g),
        (__attribute__((address_space(3))) void*)(l), 16, 0, 0);
}

// ---------------------------------------------------------------------------
// pack_a: X [4096][2048] fp32 -> Xp tiled fp16. grid (32 mt, 32 kt) x 256.
// ---------------------------------------------------------------------------
__global__ __launch_bounds__(256) void pack_a(
    const float* __restrict__ src, ushortT* __restrict__ dst)
{
    const int mt = blockIdx.x, kt = blockIdx.y;
    const int t = threadIdx.x;
    const int kq = t & 15;
    const int r0 = t >> 4;
    ushortT* tile = dst + ((size_t)(mt * 32 + kt)) * 8192;
#pragma unroll
    for (int rr = 0; rr < 8; ++rr) {
        const int row = r0 + rr * 16;
        const float4 v = *(const float4*)(src + (size_t)(mt * 128 + row) * Hc + kt * 64 + kq * 4);
        _Float16 h[4] = {(_Float16)v.x, (_Float16)v.y, (_Float16)v.z, (_Float16)v.w};
        const int gid = kq >> 1, halfg = kq & 1;
        const int gp = gid ^ (row & 7);
        *(uint2*)(tile + (size_t)row * 64 + gp * 8 + halfg * 4) = *(uint2*)h;
    }
}

// ---------------------------------------------------------------------------
// pack_b: W [k][n] fp32 -> B-operand tiled fp16. grid (16 nt, 32 kt, 4).
// ---------------------------------------------------------------------------
__global__ __launch_bounds__(256) void pack_b(
    const float* __restrict__ W0, const float* __restrict__ W1,
    const float* __restrict__ W2, const float* __restrict__ W3,
    ushortT* __restrict__ dst)
{
    const int nt = blockIdx.x, kt = blockIdx.y, which = blockIdx.z;
    const float* W = (which == 0) ? W0 : (which == 1) ? W1 : (which == 2) ? W2 : W3;
    const int t = threadIdx.x;
    const int n = t & 127;
    const int g0 = (t >> 7) * 4;
    ushortT* tile = dst + (size_t)which * 4194304 + ((size_t)(nt * 32 + kt)) * 8192;
#pragma unroll
    for (int gi = 0; gi < 4; ++gi) {
        const int g = g0 + gi;
        _Float16 h[8];
#pragma unroll
        for (int j = 0; j < 8; ++j)
            h[j] = (_Float16)W[(size_t)(kt * 64 + g * 8 + j) * Hc + nt * 128 + n];
        const int gp = g ^ (n & 7);
        *(uint4*)(tile + (size_t)n * 64 + gp * 8) = *(uint4*)h;
    }
}

// ---------------------------------------------------------------------------
// GEMM core macros: 128x128 tile, BK=64, 4 waves x 64x64 quadrant.
// ---------------------------------------------------------------------------
#define GEMM_PROLOGUE()                                                        \
    __shared__ __align__(16) ushortT As[8192], Bs[8192];                       \
    const int tid = threadIdx.x, wv_ = tid >> 6, lane = tid & 63;              \
    const int lane16 = lane & 15, quad = lane >> 4;                            \
    const int quad4 = quad * 4;                                                \
    const int wm = (wv_ & 1) * 64, wn = (wv_ >> 1) * 64;                       \
    int aoff[4][2], boff[4][2];                                                \
    _Pragma("unroll") for (int mi = 0; mi < 4; ++mi)                           \
        _Pragma("unroll") for (int kf = 0; kf < 2; ++kf) {                     \
            const int ra = wm + mi * 16 + lane16;                              \
            aoff[mi][kf] = ra * 64 + (((kf * 4 + quad) ^ (ra & 7)) << 3);      \
            const int rb = wn + mi * 16 + lane16;                              \
            boff[mi][kf] = rb * 64 + (((kf * 4 + quad) ^ (rb & 7)) << 3);      \
        }                                                                      \
    f32x4 acc[4][4];                                                           \
    _Pragma("unroll") for (int i = 0; i < 4; ++i)                              \
        _Pragma("unroll") for (int j = 0; j < 4; ++j) {                        \
            acc[i][j][0] = 0.f; acc[i][j][1] = 0.f;                            \
            acc[i][j][2] = 0.f; acc[i][j][3] = 0.f; }                          \
    ushortT* asd = &As[wv_ * 2048];                                            \
    ushortT* bsd = &Bs[wv_ * 2048];

#define GEMM_KLOOP(at, bt)                                                     \
    for (int kt2 = 0; kt2 < 32; ++kt2) {                                       \
        _Pragma("unroll") for (int i = 0; i < 4; ++i) {                        \
            load_lds16(at + i * 512 + lane * 8, asd + i * 512);                \
            load_lds16(bt + i * 512 + lane * 8, bsd + i * 512);                \
        }                                                                      \
        at += 8192; bt += 8192;                                                \
        __syncthreads();                                                       \
        _Pragma("unroll") for (int kf = 0; kf < 2; ++kf) {                     \
            f16x8 a[4], b[4];                                                  \
            _Pragma("unroll") for (int mi = 0; mi < 4; ++mi)                   \
                a[mi] = *(const f16x8*)&As[aoff[mi][kf]];                      \
            _Pragma("unroll") for (int nj = 0; nj < 4; ++nj)                   \
                b[nj] = *(const f16x8*)&Bs[boff[nj][kf]];                      \
            _Pragma("unroll") for (int nj = 0; nj < 4; ++nj)                   \
                _Pragma("unroll") for (int mi = 0; mi < 4; ++mi)               \
                    acc[mi][nj] = MFMAH(a[mi], b[nj], acc[mi][nj]);            \
        }                                                                      \
        __syncthreads();                                                       \
    }

// ---------------------------------------------------------------------------
// Fused QKV projection. grid = (48, 32). K/V epilogues write attn tile images.
// ---------------------------------------------------------------------------
__global__ __launch_bounds__(256) void qkv_gemm(
    const ushortT* __restrict__ Xp, const ushortT* __restrict__ Wall,
    const float* __restrict__ bq, const float* __restrict__ bk,
    const float* __restrict__ bv,
    ushortT* __restrict__ Qd, ushortT* __restrict__ Kd, ushortT* __restrict__ Vt)
{
    const int which = blockIdx.x >> 4;
    const int nt = blockIdx.x & 15;
    const int mt = blockIdx.y;
    const ushortT* Wp = Wall + (size_t)which * 4194304;
    const float* bias = (which == 0) ? bq : (which == 1) ? bk : bv;

    GEMM_PROLOGUE();

    const ushortT* at = Xp + (size_t)(mt * 32) * 8192 + wv_ * 2048;
    const ushortT* bt = Wp + (size_t)(nt * 32) * 8192 + wv_ * 2048;
    GEMM_KLOOP(at, bt);

    const float QS = 0.08838834764831845f * 1.4426950408889634f; // 1/sqrt(D)*log2e
#pragma unroll
    for (int nj = 0; nj < 4; ++nj) {
        const int col = nt * 128 + wn + nj * 16 + lane16;
        const float bb = bias[col];
        const int hh = col >> 7, dd = col & 127;
#pragma unroll
        for (int mi = 0; mi < 4; ++mi)
#pragma unroll
            for (int r = 0; r < 4; ++r) {
                const int m = mt * 128 + wm + mi * 16 + quad4 + r;
                const int b = m >> 11, s = m & 2047;
                const float v = acc[mi][nj][r] + bb;
                const size_t bhb = (size_t)(b * NHc + hh) * (Sc * Dc);
                if (which == 0) {
                    Qd[bhb + (size_t)s * Dc + dd] = f2h(v * QS);
                } else if (which == 1) {
                    // K tile image: [64 s][128 d], granule g=d>>3 swizzled by s&7
                    const int t2 = s >> 6, sin = s & 63;
                    Kd[bhb + (size_t)t2 * 8192 + sin * 128 +
                       (((dd >> 3) ^ (sin & 7)) << 3) + (dd & 7)] = f2h(v);
                } else {
                    // V tile image: [128 d][64 s], granule g=sin>>3 swizzled by d&7
                    const int t2 = s >> 6, sin = s & 63;
                    Vt[bhb + (size_t)t2 * 8192 + dd * 64 +
                       (((sin >> 3) ^ (dd & 7)) << 3) + (sin & 7)] = f2h(v);
                }
            }
    }
}

// ---------------------------------------------------------------------------
// Flash attention. Block = 128 q-rows x 4 waves (32-row strips), kv tile 64.
// K/V staged via global_load_lds DMA from pre-swizzled tiles. grid (16,16,2).
// ---------------------------------------------------------------------------
#define SSTR 68   // S chunk row stride in floats (de-aliased banks, 16B-aligned)

__global__ __launch_bounds__(256, 2) void attn(
    const ushortT* __restrict__ Qd, const ushortT* __restrict__ Kt,
    const ushortT* __restrict__ Vt, ushortT* __restrict__ AOp)
{
    const int qt = blockIdx.x, hh = blockIdx.y, bb = blockIdx.z;
    const ushortT* Qp  = Qd + ((size_t)(bb * NHc + hh)) * Sc * Dc;
    const ushortT* Kbh = Kt + ((size_t)(bb * NHc + hh)) * Sc * Dc;
    const ushortT* Vbh = Vt + ((size_t)(bb * NHc + hh)) * Sc * Dc;

    __shared__ __align__(16) ushortT Ks[8192];        // 64 kv x 128 d tile image
    __shared__ __align__(16) ushortT Vs[8192];        // 128 d x 64 kv tile image
    __shared__ __align__(16) float   Sbuf[4][16 * SSTR]; // per-wave S chunk fp32
    __shared__ __align__(16) ushortT Pbuf[4][1024];   // per-wave P chunk f16
    __shared__ float alphas[4][32], linvs[4][32];

    const int tid = threadIdx.x, wv_ = tid >> 6, lane = tid & 63;
    const int lane16 = lane & 15, quad = lane >> 4;
    const int quad8 = quad * 8, quad4 = quad * 4;
    const int s0 = qt * 128 + wv_ * 32;

    // Q frags in registers (pre-scaled by 1/sqrt(D)*log2e)
    f16x8 q[2][4];
#pragma unroll
    for (int mi = 0; mi < 2; ++mi)
#pragma unroll
        for (int kf = 0; kf < 4; ++kf)
            q[mi][kf] = *(const f16x8*)(Qp + (size_t)(s0 + mi * 16 + lane16) * Dc + kf * 32 + quad8);

    f32x4 o[2][8];
#pragma unroll
    for (int mi = 0; mi < 2; ++mi)
#pragma unroll
        for (int dj = 0; dj < 8; ++dj) { o[mi][dj][0] = 0.f; o[mi][dj][1] = 0.f; o[mi][dj][2] = 0.f; o[mi][dj][3] = 0.f; }

    float m_run[2] = {-1e30f, -1e30f}, l_run[2] = {0.f, 0.f};
    const int srow = lane >> 2;         // softmax: lane owns this chunk row
    const int scol = (lane & 3) * 16;   // and this 16-col slice
    float*   Sw = Sbuf[wv_];
    ushortT* Pw = Pbuf[wv_];

    for (int nt = 0; nt < 32; ++nt) {
        // ---- stage K/V tiles via DMA (tile image == LDS image) ----
        const ushortT* ktile = Kbh + (size_t)nt * 8192 + wv_ * 2048;
        const ushortT* vtile = Vbh + (size_t)nt * 8192 + wv_ * 2048;
        ushortT* kdst = Ks + wv_ * 2048;
        ushortT* vdst = Vs + wv_ * 2048;
#pragma unroll
        for (int i = 0; i < 4; ++i) {
            load_lds16(ktile + i * 512 + lane * 8, kdst + i * 512);
            load_lds16(vtile + i * 512 + lane * 8, vdst + i * 512);
        }
        __syncthreads();

        // ---- S = Q K^T (32 x 64 strip) ----
        f32x4 sacc[2][4];
#pragma unroll
        for (int mi = 0; mi < 2; ++mi)
#pragma unroll
            for (int nj = 0; nj < 4; ++nj) { sacc[mi][nj][0] = 0.f; sacc[mi][nj][1] = 0.f; sacc[mi][nj][2] = 0.f; sacc[mi][nj][3] = 0.f; }
#pragma unroll
        for (int kf = 0; kf < 4; ++kf) {
            f16x8 kb[4];
#pragma unroll
            for (int nj = 0; nj < 4; ++nj) {
                const int row = nj * 16 + lane16;
                kb[nj] = *(const f16x8*)&Ks[row * 128 + (((kf * 4 + quad) ^ (row & 7)) << 3)];
            }
#pragma unroll
            for (int mi = 0; mi < 2; ++mi)
#pragma unroll
                for (int nj = 0; nj < 4; ++nj)
                    sacc[mi][nj] = MFMAH(q[mi][kf], kb[nj], sacc[mi][nj]);
        }

        // ---- V frags cached in registers (used by both chunks) ----
        f16x8 vb[2][8];
#pragma unroll
        for (int kf2 = 0; kf2 < 2; ++kf2)
#pragma unroll
            for (int dj = 0; dj < 8; ++dj) {
                const int row = dj * 16 + lane16;
                vb[kf2][dj] = *(const f16x8*)&Vs[row * 64 + (((kf2 * 4 + quad) ^ (row & 7)) << 3)];
            }

        // ---- per 16-row chunk: spill / softmax / P / rescale / PV ----
#pragma unroll
        for (int mi = 0; mi < 2; ++mi) {
            // spill chunk (rows 0..15 local = quad4+r, cols nj*16+lane16)
#pragma unroll
            for (int nj = 0; nj < 4; ++nj)
#pragma unroll
                for (int r = 0; r < 4; ++r)
                    Sw[(quad4 + r) * SSTR + nj * 16 + lane16] = sacc[mi][nj][r];
            // softmax: lane owns (srow, scol..scol+15)
            float sv[16];
#pragma unroll
            for (int i = 0; i < 4; ++i)
                *(float4*)&sv[i * 4] = *(const float4*)&Sw[srow * SSTR + scol + i * 4];
            float mx = sv[0];
#pragma unroll
            for (int i = 1; i < 16; ++i) mx = fmaxf(mx, sv[i]);
            mx = fmaxf(mx, __shfl_xor(mx, 1));
            mx = fmaxf(mx, __shfl_xor(mx, 2));
            const float mnew = fmaxf(m_run[mi], mx);
            const float alpha = exp2f(m_run[mi] - mnew);
            m_run[mi] = mnew;
            float sum = 0.f;
#pragma unroll
            for (int i = 0; i < 16; ++i) { const float p = exp2f(sv[i] - mnew); sv[i] = p; sum += p; }
            sum += __shfl_xor(sum, 1);
            sum += __shfl_xor(sum, 2);
            l_run[mi] = l_run[mi] * alpha + sum;
            if ((lane & 3) == 0) alphas[wv_][mi * 16 + srow] = alpha;
            // P -> f16, A-operand tile image [16 rows][64 cols] swizzled
            uint32_t pu[8];
#pragma unroll
            for (int i = 0; i < 8; ++i)
                pu[i] = (uint32_t)f2h(sv[2 * i]) | ((uint32_t)f2h(sv[2 * i + 1]) << 16);
#pragma unroll
            for (int j = 0; j < 2; ++j) {
                const int g = (scol >> 3) + j;
                *(uint4*)&Pw[srow * 64 + ((g ^ (srow & 7)) << 3)] = *(uint4*)&pu[j * 4];
            }
            // rescale O[mi]
#pragma unroll
            for (int r = 0; r < 4; ++r) {
                const float av = alphas[wv_][mi * 16 + quad4 + r];
#pragma unroll
                for (int dj = 0; dj < 8; ++dj) o[mi][dj][r] *= av;
            }
            // O[mi] += P V
#pragma unroll
            for (int kf2 = 0; kf2 < 2; ++kf2) {
                const f16x8 pa = *(const f16x8*)&Pw[lane16 * 64 + (((kf2 * 4 + quad) ^ (lane16 & 7)) << 3)];
#pragma unroll
                for (int dj = 0; dj < 8; ++dj)
                    o[mi][dj] = MFMAH(pa, vb[kf2][dj], o[mi][dj]);
            }
        }
        __syncthreads();
    }

    // ---- epilogue: /l, write AO in packed tiled-swizzled A layout ----
    if ((lane & 3) == 0) {
        linvs[wv_][srow]      = 1.f / l_run[0];
        linvs[wv_][16 + srow] = 1.f / l_run[1];
    }
#pragma unroll
    for (int mi = 0; mi < 2; ++mi)
#pragma unroll
        for (int r = 0; r < 4; ++r) {
            const int row = mi * 16 + quad4 + r;
            const float li = linvs[wv_][row];
            const int mrow = bb * Sc + qt * 128 + wv_ * 32 + row;
            const int mtile = mrow >> 7, rin = mrow & 127;
#pragma unroll
            for (int dj = 0; dj < 8; ++dj) {
                const int kt2 = hh * 2 + (dj >> 2);
                const int colin = (dj & 3) * 16 + lane16;
                const int g = colin >> 3, e = colin & 7;
                const int gp = g ^ (rin & 7);
                AOp[((size_t)(mtile * 32 + kt2)) * 8192 + rin * 64 + gp * 8 + e] =
                    f2h(o[mi][dj][r] * li);
            }
        }
}

// ---------------------------------------------------------------------------
// Output projection: out = AO @ Wo + bo. grid = (16, 32).
// ---------------------------------------------------------------------------
__global__ __launch_bounds__(256) void out_gemm(
    const ushortT* __restrict__ AOp, const ushortT* __restrict__ Wop,
    const float* __restrict__ bo, float* __restrict__ out)
{
    const int nt = blockIdx.x;
    const int mt = blockIdx.y;

    GEMM_PROLOGUE();

    const ushortT* at = AOp + (size_t)(mt * 32) * 8192 + wv_ * 2048;
    const ushortT* bt = Wop + (size_t)(nt * 32) * 8192 + wv_ * 2048;
    GEMM_KLOOP(at, bt);

#pragma unroll
    for (int nj = 0; nj < 4; ++nj) {
        const int col = nt * 128 + wn + nj * 16 + lane16;
        const float bb = bo[col];
#pragma unroll
        for (int mi = 0; mi < 4; ++mi)
#pragma unroll
            for (int r = 0; r < 4; ++r) {
                const int m = mt * 128 + wm + mi * 16 + quad4 + r;
                out[(size_t)m * Hc + col] = acc[mi][nj][r] + bb;
            }
    }
}

// ---------------------------------------------------------------------------
extern "C" void kernel_launch(void* const* d_in, const int* in_sizes, int n_in,
                              void* d_out, int out_size, void* d_ws, size_t ws_size,
                              hipStream_t stream) {
    (void)in_sizes; (void)n_in; (void)out_size; (void)ws_size;

    const float* X  = (const float*)d_in[0];
    const float* Wq = (const float*)d_in[1];
    const float* bq = (const float*)d_in[2];
    const float* Wk = (const float*)d_in[3];
    const float* bk = (const float*)d_in[4];
    const float* Wv = (const float*)d_in[5];
    const float* bv = (const float*)d_in[6];
    const float* Wo = (const float*)d_in[7];
    const float* bo = (const float*)d_in[8];
    float* out = (float*)d_out;

    ushortT* ws = (ushortT*)d_ws;
    const size_t E = (size_t)Mc * Hc;      // 8388608
    const size_t WE = (size_t)Hc * Hc;     // 4194304
    ushortT* Xp   = ws;
    ushortT* Wall = Xp + E;
    ushortT* Qd   = Wall + 4 * WE;
    ushortT* Kd   = Qd + E;
    ushortT* Vtp  = Kd + E;
    ushortT* AOp  = Vtp + E;               // total 117.4 MB

    pack_a<<<dim3(32, 32), 256, 0, stream>>>(X, Xp);
    pack_b<<<dim3(16, 32, 4), 256, 0, stream>>>(Wq, Wk, Wv, Wo, Wall);
    qkv_gemm<<<dim3(48, 32), 256, 0, stream>>>(Xp, Wall, bq, bk, bv, Qd, Kd, Vtp);
    attn<<<dim3(16, NHc, Bc), 256, 0, stream>>>(Qd, Kd, Vtp, AOp);
    out_gemm<<<dim3(16, 32), 256, 0, stream>>>(AOp, Wall + 3 * WE, bo, out);
}

// Round 5
// 446.599 us; speedup vs baseline: 7.4076x; 1.0142x over previous
//
#include <hip/hip_runtime.h>
#include <hip/hip_bf16.h>
#include <stdint.h>

// MHSA on MI355X: B=2, S=2048, H=2048, NH=16, D=128. Round 5.
//   attn rewritten with transposed-S formulation: S^T = K*Q^T puts q on
//   lane16 and kv on quad4+r -> softmax is all-register (2 shuffles for the
//   cross-quad kv reduce, alpha/m/l per-lane). P does ONE LDS pass (C->B
//   operand transform). O accumulates as O^T[d][q]. BM=64, 2-wave blocks,
//   grid 1024 with XCD-aware (b,h) grouping; LDS 40KB -> 4 blocks/CU.
//   qkv_gemm/out_gemm/packs unchanged from round 4.
// ws: Xp | Wq..Wo | Qd Kd Vt | AOp = 117.4 MB.

#define Bc 2
#define Sc 2048
#define Hc 2048
#define NHc 16
#define Dc 128
#define Mc 4096

typedef unsigned short ushortT;
typedef float f32x4 __attribute__((ext_vector_type(4)));
typedef _Float16 f16x8 __attribute__((ext_vector_type(8)));

#define MFMAH(a, b, c) __builtin_amdgcn_mfma_f32_16x16x32_f16((a), (b), (c), 0, 0, 0)

static __device__ __forceinline__ ushortT f2h(float x) {
    _Float16 h = (_Float16)x;
    return __builtin_bit_cast(unsigned short, h);
}

static __device__ __forceinline__ void load_lds16(const ushortT* g, ushortT* l) {
    __builtin_amdgcn_global_load_lds(
        (__attribute__((address_space(1))) void*)(g),
        (__attribute__((address_space(3))) void*)(l), 16, 0, 0);
}

// ---------------------------------------------------------------------------
// pack_a: X [4096][2048] fp32 -> Xp tiled fp16. grid (32 mt, 32 kt) x 256.
// ---------------------------------------------------------------------------
__global__ __launch_bounds__(256) void pack_a(
    const float* __restrict__ src, ushortT* __restrict__ dst)
{
    const int mt = blockIdx.x, kt = blockIdx.y;
    const int t = threadIdx.x;
    const int kq = t & 15;
    const int r0 = t >> 4;
    ushortT* tile = dst + ((size_t)(mt * 32 + kt)) * 8192;
#pragma unroll
    for (int rr = 0; rr < 8; ++rr) {
        const int row = r0 + rr * 16;
        const float4 v = *(const float4*)(src + (size_t)(mt * 128 + row) * Hc + kt * 64 + kq * 4);
        _Float16 h[4] = {(_Float16)v.x, (_Float16)v.y, (_Float16)v.z, (_Float16)v.w};
        const int gid = kq >> 1, halfg = kq & 1;
        const int gp = gid ^ (row & 7);
        *(uint2*)(tile + (size_t)row * 64 + gp * 8 + halfg * 4) = *(uint2*)h;
    }
}

// ---------------------------------------------------------------------------
// pack_b: W [k][n] fp32 -> B-operand tiled fp16. grid (16 nt, 32 kt, 4).
// ---------------------------------------------------------------------------
__global__ __launch_bounds__(256) void pack_b(
    const float* __restrict__ W0, const float* __restrict__ W1,
    const float* __restrict__ W2, const float* __restrict__ W3,
    ushortT* __restrict__ dst)
{
    const int nt = blockIdx.x, kt = blockIdx.y, which = blockIdx.z;
    const float* W = (which == 0) ? W0 : (which == 1) ? W1 : (which == 2) ? W2 : W3;
    const int t = threadIdx.x;
    const int n = t & 127;
    const int g0 = (t >> 7) * 4;
    ushortT* tile = dst + (size_t)which * 4194304 + ((size_t)(nt * 32 + kt)) * 8192;
#pragma unroll
    for (int gi = 0; gi < 4; ++gi) {
        const int g = g0 + gi;
        _Float16 h[8];
#pragma unroll
        for (int j = 0; j < 8; ++j)
            h[j] = (_Float16)W[(size_t)(kt * 64 + g * 8 + j) * Hc + nt * 128 + n];
        const int gp = g ^ (n & 7);
        *(uint4*)(tile + (size_t)n * 64 + gp * 8) = *(uint4*)h;
    }
}

// ---------------------------------------------------------------------------
// GEMM core macros: 128x128 tile, BK=64, 4 waves x 64x64 quadrant.
// ---------------------------------------------------------------------------
#define GEMM_PROLOGUE()                                                        \
    __shared__ __align__(16) ushortT As[8192], Bs[8192];                       \
    const int tid = threadIdx.x, wv_ = tid >> 6, lane = tid & 63;              \
    const int lane16 = lane & 15, quad = lane >> 4;                            \
    const int quad4 = quad * 4;                                                \
    const int wm = (wv_ & 1) * 64, wn = (wv_ >> 1) * 64;                       \
    int aoff[4][2], boff[4][2];                                                \
    _Pragma("unroll") for (int mi = 0; mi < 4; ++mi)                           \
        _Pragma("unroll") for (int kf = 0; kf < 2; ++kf) {                     \
            const int ra = wm + mi * 16 + lane16;                              \
            aoff[mi][kf] = ra * 64 + (((kf * 4 + quad) ^ (ra & 7)) << 3);      \
            const int rb = wn + mi * 16 + lane16;                              \
            boff[mi][kf] = rb * 64 + (((kf * 4 + quad) ^ (rb & 7)) << 3);      \
        }                                                                      \
    f32x4 acc[4][4];                                                           \
    _Pragma("unroll") for (int i = 0; i < 4; ++i)                              \
        _Pragma("unroll") for (int j = 0; j < 4; ++j) {                        \
            acc[i][j][0] = 0.f; acc[i][j][1] = 0.f;                            \
            acc[i][j][2] = 0.f; acc[i][j][3] = 0.f; }                          \
    ushortT* asd = &As[wv_ * 2048];                                            \
    ushortT* bsd = &Bs[wv_ * 2048];

#define GEMM_KLOOP(at, bt)                                                     \
    for (int kt2 = 0; kt2 < 32; ++kt2) {                                       \
        _Pragma("unroll") for (int i = 0; i < 4; ++i) {                        \
            load_lds16(at + i * 512 + lane * 8, asd + i * 512);                \
            load_lds16(bt + i * 512 + lane * 8, bsd + i * 512);                \
        }                                                                      \
        at += 8192; bt += 8192;                                                \
        __syncthreads();                                                       \
        _Pragma("unroll") for (int kf = 0; kf < 2; ++kf) {                     \
            f16x8 a[4], b[4];                                                  \
            _Pragma("unroll") for (int mi = 0; mi < 4; ++mi)                   \
                a[mi] = *(const f16x8*)&As[aoff[mi][kf]];                      \
            _Pragma("unroll") for (int nj = 0; nj < 4; ++nj)                   \
                b[nj] = *(const f16x8*)&Bs[boff[nj][kf]];                      \
            _Pragma("unroll") for (int nj = 0; nj < 4; ++nj)                   \
                _Pragma("unroll") for (int mi = 0; mi < 4; ++mi)               \
                    acc[mi][nj] = MFMAH(a[mi], b[nj], acc[mi][nj]);            \
        }                                                                      \
        __syncthreads();                                                       \
    }

// ---------------------------------------------------------------------------
// Fused QKV projection. grid = (48, 32). K/V epilogues write attn tile images.
// ---------------------------------------------------------------------------
__global__ __launch_bounds__(256) void qkv_gemm(
    const ushortT* __restrict__ Xp, const ushortT* __restrict__ Wall,
    const float* __restrict__ bq, const float* __restrict__ bk,
    const float* __restrict__ bv,
    ushortT* __restrict__ Qd, ushortT* __restrict__ Kd, ushortT* __restrict__ Vt)
{
    const int which = blockIdx.x >> 4;
    const int nt = blockIdx.x & 15;
    const int mt = blockIdx.y;
    const ushortT* Wp = Wall + (size_t)which * 4194304;
    const float* bias = (which == 0) ? bq : (which == 1) ? bk : bv;

    GEMM_PROLOGUE();

    const ushortT* at = Xp + (size_t)(mt * 32) * 8192 + wv_ * 2048;
    const ushortT* bt = Wp + (size_t)(nt * 32) * 8192 + wv_ * 2048;
    GEMM_KLOOP(at, bt);

    const float QS = 0.08838834764831845f * 1.4426950408889634f; // 1/sqrt(D)*log2e
#pragma unroll
    for (int nj = 0; nj < 4; ++nj) {
        const int col = nt * 128 + wn + nj * 16 + lane16;
        const float bb = bias[col];
        const int hh = col >> 7, dd = col & 127;
#pragma unroll
        for (int mi = 0; mi < 4; ++mi)
#pragma unroll
            for (int r = 0; r < 4; ++r) {
                const int m = mt * 128 + wm + mi * 16 + quad4 + r;
                const int b = m >> 11, s = m & 2047;
                const float v = acc[mi][nj][r] + bb;
                const size_t bhb = (size_t)(b * NHc + hh) * (Sc * Dc);
                if (which == 0) {
                    Qd[bhb + (size_t)s * Dc + dd] = f2h(v * QS);
                } else if (which == 1) {
                    // K tile image: [64 s][128 d], granule g=d>>3 swizzled by s&7
                    const int t2 = s >> 6, sin = s & 63;
                    Kd[bhb + (size_t)t2 * 8192 + sin * 128 +
                       (((dd >> 3) ^ (sin & 7)) << 3) + (dd & 7)] = f2h(v);
                } else {
                    // V tile image: [128 d][64 s], granule g=sin>>3 swizzled by d&7
                    const int t2 = s >> 6, sin = s & 63;
                    Vt[bhb + (size_t)t2 * 8192 + dd * 64 +
                       (((sin >> 3) ^ (dd & 7)) << 3) + (sin & 7)] = f2h(v);
                }
            }
    }
}

// ---------------------------------------------------------------------------
// Flash attention, transposed-S formulation. Block = 64 q-rows x 2 waves
// (32-q strips), kv tile 64. grid = 1024 1-D, XCD-grouped decode.
// S^T = K*Q^T: lane16 = q, quad4+r = kv -> register softmax.
// O^T[d][q] = V^T * P; single LDS pass for P (C->B operand transform).
// ---------------------------------------------------------------------------
__global__ __launch_bounds__(128, 2) void attn(
    const ushortT* __restrict__ Qd, const ushortT* __restrict__ Kt,
    const ushortT* __restrict__ Vt, ushortT* __restrict__ AOp)
{
    // XCD-aware decode: all 32 q-blocks of one (b,h) share id%8 (-> same XCD)
    const int id = blockIdx.x;                 // 0..1023
    const int slot = id >> 3;                  // 0..127
    const int pair = (id & 7) + ((slot >> 5) << 3);  // 0..31
    const int qt = slot & 31;                  // 0..31 (64-row q tiles)
    const int hh = pair & 15, bb = pair >> 4;

    const ushortT* Qp  = Qd + ((size_t)(bb * NHc + hh)) * Sc * Dc;
    const ushortT* Kbh = Kt + ((size_t)(bb * NHc + hh)) * Sc * Dc;
    const ushortT* Vbh = Vt + ((size_t)(bb * NHc + hh)) * Sc * Dc;

    __shared__ __align__(16) ushortT Ks[8192];      // 64 kv x 128 d tile image
    __shared__ __align__(16) ushortT Vs[8192];      // 128 d x 64 kv tile image
    __shared__ __align__(16) ushortT Pbuf[2][2048]; // per-wave P [32 q][64 kv]

    const int tid = threadIdx.x, wv_ = tid >> 6, lane = tid & 63;
    const int lane16 = lane & 15, quad = lane >> 4;
    const int quad8 = quad * 8, quad4 = quad * 4;
    const int s0 = qt * 64 + wv_ * 32;

    // Q frags (A-layout register image == B-operand image), pre-scaled
    f16x8 q[2][4];
#pragma unroll
    for (int nj = 0; nj < 2; ++nj)
#pragma unroll
        for (int kf = 0; kf < 4; ++kf)
            q[nj][kf] = *(const f16x8*)(Qp + (size_t)(s0 + nj * 16 + lane16) * Dc + kf * 32 + quad8);

    // O^T accumulator: o[dj][nj], D rows = d (quad4+r), cols = q (lane16)
    f32x4 o[8][2];
#pragma unroll
    for (int dj = 0; dj < 8; ++dj)
#pragma unroll
        for (int nj = 0; nj < 2; ++nj) { o[dj][nj][0] = 0.f; o[dj][nj][1] = 0.f; o[dj][nj][2] = 0.f; o[dj][nj][3] = 0.f; }

    float m_run[2] = {-1e30f, -1e30f}, l_run[2] = {0.f, 0.f};
    ushortT* Pw = Pbuf[wv_];

    for (int nt = 0; nt < 32; ++nt) {
        // ---- stage K/V tile images via DMA (each wave half of each) ----
        const ushortT* ktile = Kbh + (size_t)nt * 8192 + wv_ * 4096;
        const ushortT* vtile = Vbh + (size_t)nt * 8192 + wv_ * 4096;
#pragma unroll
        for (int i = 0; i < 8; ++i) {
            load_lds16(ktile + i * 512 + lane * 8, Ks + wv_ * 4096 + i * 512);
            load_lds16(vtile + i * 512 + lane * 8, Vs + wv_ * 4096 + i * 512);
        }
        __syncthreads();

        // ---- S^T = K * Q^T : sacc[mi=kv-tile][nj=q-tile] ----
        f32x4 sacc[4][2];
#pragma unroll
        for (int mi = 0; mi < 4; ++mi)
#pragma unroll
            for (int nj = 0; nj < 2; ++nj) { sacc[mi][nj][0] = 0.f; sacc[mi][nj][1] = 0.f; sacc[mi][nj][2] = 0.f; sacc[mi][nj][3] = 0.f; }
#pragma unroll
        for (int kf = 0; kf < 4; ++kf) {
            f16x8 kb[4];
#pragma unroll
            for (int mi = 0; mi < 4; ++mi) {
                const int row = mi * 16 + lane16;
                kb[mi] = *(const f16x8*)&Ks[row * 128 + (((kf * 4 + quad) ^ (row & 7)) << 3)];
            }
#pragma unroll
            for (int mi = 0; mi < 4; ++mi)
#pragma unroll
                for (int nj = 0; nj < 2; ++nj)
                    sacc[mi][nj] = MFMAH(kb[mi], q[nj][kf], sacc[mi][nj]);
        }

        // ---- register softmax per q-tile (kv reduce: 16 regs + 2 shuffles) ----
        float alpha_[2];
#pragma unroll
        for (int nj = 0; nj < 2; ++nj) {
            float mx = sacc[0][nj][0];
#pragma unroll
            for (int mi = 0; mi < 4; ++mi)
#pragma unroll
                for (int r = 0; r < 4; ++r) mx = fmaxf(mx, sacc[mi][nj][r]);
            mx = fmaxf(mx, __shfl_xor(mx, 16));
            mx = fmaxf(mx, __shfl_xor(mx, 32));
            const float mnew = fmaxf(m_run[nj], mx);
            alpha_[nj] = exp2f(m_run[nj] - mnew);
            m_run[nj] = mnew;
            float sum = 0.f;
#pragma unroll
            for (int mi = 0; mi < 4; ++mi)
#pragma unroll
                for (int r = 0; r < 4; ++r) {
                    const float p = exp2f(sacc[mi][nj][r] - mnew);
                    sacc[mi][nj][r] = p;
                    sum += p;
                }
            sum += __shfl_xor(sum, 16);
            sum += __shfl_xor(sum, 32);
            l_run[nj] = l_run[nj] * alpha_[nj] + sum;
            // P -> f16, single LDS pass into B-operand image [q row][kv]
            const int prow = nj * 16 + lane16;
#pragma unroll
            for (int mi = 0; mi < 4; ++mi) {
                uint2 u;
                u.x = (uint32_t)f2h(sacc[mi][nj][0]) | ((uint32_t)f2h(sacc[mi][nj][1]) << 16);
                u.y = (uint32_t)f2h(sacc[mi][nj][2]) | ((uint32_t)f2h(sacc[mi][nj][3]) << 16);
                const int g = mi * 2 + (quad >> 1);        // kv granule
                *(uint2*)&Pw[prow * 64 + ((g ^ (prow & 7)) << 3) + (quad & 1) * 4] = u;
            }
        }

        // ---- rescale O ----
#pragma unroll
        for (int dj = 0; dj < 8; ++dj)
#pragma unroll
            for (int nj = 0; nj < 2; ++nj) {
                const float av = alpha_[nj];
                o[dj][nj][0] *= av; o[dj][nj][1] *= av;
                o[dj][nj][2] *= av; o[dj][nj][3] *= av;
            }

        // ---- O^T += V^T * P ----
#pragma unroll
        for (int kf2 = 0; kf2 < 2; ++kf2) {
            f16x8 pb[2];
#pragma unroll
            for (int nj = 0; nj < 2; ++nj) {
                const int row = nj * 16 + lane16;
                pb[nj] = *(const f16x8*)&Pw[row * 64 + (((kf2 * 4 + quad) ^ (row & 7)) << 3)];
            }
#pragma unroll
            for (int dj = 0; dj < 8; ++dj) {
                const int row = dj * 16 + lane16;
                const f16x8 vb = *(const f16x8*)&Vs[row * 64 + (((kf2 * 4 + quad) ^ (row & 7)) << 3)];
#pragma unroll
                for (int nj = 0; nj < 2; ++nj)
                    o[dj][nj] = MFMAH(vb, pb[nj], o[dj][nj]);
            }
        }
        __syncthreads();
    }

    // ---- epilogue: /l (in-register), write AO in packed A-operand image ----
#pragma unroll
    for (int nj = 0; nj < 2; ++nj) {
        const float inv = 1.f / l_run[nj];
        const int m = bb * Sc + qt * 64 + wv_ * 32 + nj * 16 + lane16;
        const int mtile = m >> 7, rin = m & 127;
#pragma unroll
        for (int dj = 0; dj < 8; ++dj) {
            // d = dj*16 + quad4 + r; r=0..3 are contiguous within one granule
            const int ktile = hh * 2 + (dj >> 2);
            const int cin0 = (dj & 3) * 16 + quad4;
            const int g = cin0 >> 3, e0 = cin0 & 7;
            uint2 u;
            u.x = (uint32_t)f2h(o[dj][nj][0] * inv) | ((uint32_t)f2h(o[dj][nj][1] * inv) << 16);
            u.y = (uint32_t)f2h(o[dj][nj][2] * inv) | ((uint32_t)f2h(o[dj][nj][3] * inv) << 16);
            *(uint2*)&AOp[((size_t)(mtile * 32 + ktile)) * 8192 + rin * 64 +
                          ((g ^ (rin & 7)) << 3) + e0] = u;
        }
    }
}

// ---------------------------------------------------------------------------
// Output projection: out = AO @ Wo + bo. grid = (16, 32).
// ---------------------------------------------------------------------------
__global__ __launch_bounds__(256) void out_gemm(
    const ushortT* __restrict__ AOp, const ushortT* __restrict__ Wop,
    const float* __restrict__ bo, float* __restrict__ out)
{
    const int nt = blockIdx.x;
    const int mt = blockIdx.y;

    GEMM_PROLOGUE();

    const ushortT* at = AOp + (size_t)(mt * 32) * 8192 + wv_ * 2048;
    const ushortT* bt = Wop + (size_t)(nt * 32) * 8192 + wv_ * 2048;
    GEMM_KLOOP(at, bt);

#pragma unroll
    for (int nj = 0; nj < 4; ++nj) {
        const int col = nt * 128 + wn + nj * 16 + lane16;
        const float bb = bo[col];
#pragma unroll
        for (int mi = 0; mi < 4; ++mi)
#pragma unroll
            for (int r = 0; r < 4; ++r) {
                const int m = mt * 128 + wm + mi * 16 + quad4 + r;
                out[(size_t)m * Hc + col] = acc[mi][nj][r] + bb;
            }
    }
}

// ---------------------------------------------------------------------------
extern "C" void kernel_launch(void* const* d_in, const int* in_sizes, int n_in,
                              void* d_out, int out_size, void* d_ws, size_t ws_size,
                              hipStream_t stream) {
    (void)in_sizes; (void)n_in; (void)out_size; (void)ws_size;

    const float* X  = (const float*)d_in[0];
    const float* Wq = (const float*)d_in[1];
    const float* bq = (const float*)d_in[2];
    const float* Wk = (const float*)d_in[3];
    const float* bk = (const float*)d_in[4];
    const float* Wv = (const float*)d_in[5];
    const float* bv = (const float*)d_in[6];
    const float* Wo = (const float*)d_in[7];
    const float* bo = (const float*)d_in[8];
    float* out = (float*)d_out;

    ushortT* ws = (ushortT*)d_ws;
    const size_t E = (size_t)Mc * Hc;      // 8388608
    const size_t WE = (size_t)Hc * Hc;     // 4194304
    ushortT* Xp   = ws;
    ushortT* Wall = Xp + E;
    ushortT* Qd   = Wall + 4 * WE;
    ushortT* Kd   = Qd + E;
    ushortT* Vtp  = Kd + E;
    ushortT* AOp  = Vtp + E;               // total 117.4 MB

    pack_a<<<dim3(32, 32), 256, 0, stream>>>(X, Xp);
    pack_b<<<dim3(16, 32, 4), 256, 0, stream>>>(Wq, Wk, Wv, Wo, Wall);
    qkv_gemm<<<dim3(48, 32), 256, 0, stream>>>(Xp, Wall, bq, bk, bv, Qd, Kd, Vtp);
    attn<<<dim3(1024), 128, 0, stream>>>(Qd, Kd, Vtp, AOp);
    out_gemm<<<dim3(16, 32), 256, 0, stream>>>(AOp, Wall + 3 * WE, bo, out);
}